// Round 1
// baseline (1019.099 us; speedup 1.0000x reference)
//
#include <hip/hip_runtime.h>

// WaveInputEncoder on MI355X.
// Pipeline: prep (softplus/rot consts, DFT tables, weight transposes to bf16)
//   -> kernelA: embed+rotate+FTE matmul+positional phase -> residual (f32)
//   -> kernelB: truncated forward DFT (32 modes)  -> Xr,Xi
//   -> kernelC: per-(block,mode) 128x128 complex matmul + softshrink -> Or,Oi
//   -> kernelD: truncated inverse DFT + residual + LN1 -> x_ln1 (bf16)
//   -> 4 chunks x { GEMM1(bf16 MFMA)+gelu -> h(bf16), GEMM2+bias+residual -> f32 out }
//   -> LN2 in-place on d_out.
// ws usage ~154 MB.

typedef __attribute__((ext_vector_type(8))) short s16x8;
typedef __attribute__((ext_vector_type(4))) float f32x4;

__device__ __forceinline__ short f2bf(float x){
  unsigned u = __float_as_uint(x);
  unsigned r = (u + 0x7fffu + ((u >> 16) & 1u)) >> 16;   // RNE
  return (short)r;
}
__device__ __forceinline__ float bf2f(short x){
  return __uint_as_float(((unsigned)(unsigned short)x) << 16);
}

// ---------------- prep kernels ----------------
__global__ void prep_wcs_k(const float* __restrict__ mw, const float* __restrict__ po,
                           float* __restrict__ wcs){
  int i = threadIdx.x;
  if (i < 32){
    wcs[i]      = log1pf(expf(mw[i]));  // softplus
    wcs[32 + i] = cosf(po[i]);
    wcs[64 + i] = sinf(po[i]);
  }
}

__global__ __launch_bounds__(256) void prep_tab_k(float* __restrict__ ctab, float* __restrict__ stab){
  int idx = blockIdx.x * 256 + threadIdx.x;      // idx = m*4096 + t
  int m = idx >> 12, t = idx & 4095;
  int r = (m * t) & 4095;                        // exact angle reduction
  float ang = (float)r * 1.5339807878856412e-3f; // 2*pi/4096
  float s, c; sincosf(ang, &s, &c);
  ctab[idx] = c; stab[idx] = s;
}

// transpose fp32 (R x C) -> bf16 (C x R), 64x64 LDS tiles
__global__ __launch_bounds__(256) void transpose_bf16_k(const float* __restrict__ src,
                                                        short* __restrict__ dst,
                                                        int R, int C){
  __shared__ float tile[64][65];
  int c0 = blockIdx.x * 64, r0 = blockIdx.y * 64;
  for (int i = 0; i < 16; ++i){
    int idx = i * 256 + threadIdx.x;
    int rr = idx >> 6, cc = idx & 63;
    tile[rr][cc] = src[(size_t)(r0 + rr) * C + c0 + cc];
  }
  __syncthreads();
  for (int i = 0; i < 16; ++i){
    int idx = i * 256 + threadIdx.x;
    int cc = idx >> 6, rr = idx & 63;
    dst[(size_t)(c0 + cc) * R + r0 + rr] = f2bf(tile[rr][cc]);
  }
}

// ---------------- kernel A: embed + rotate + FTE + positional phase ----------------
// grid 4096 (= B*T/4 tokens-per-block), block 256
__global__ __launch_bounds__(256) void kernelA(const int* __restrict__ tokens,
    const float* __restrict__ frw, const float* __restrict__ fiw,
    const float* __restrict__ wcs, const float* __restrict__ ftew,
    const float* __restrict__ fteb, const float* __restrict__ posph,
    float* __restrict__ xout){
  __shared__ float ffs[4][64];
  __shared__ float xs[4][1024];
  __shared__ float wsh[96];
  int tid = threadIdx.x;
  int b = blockIdx.x >> 10, t0 = (blockIdx.x & 1023) * 4;
  if (tid < 96) wsh[tid] = wcs[tid];
  __syncthreads();
  if (tid < 128){
    int tk = tid >> 5, m = tid & 31;
    int tok = tokens[b * 4096 + t0 + tk];
    float w = wsh[m];
    float re = frw[(size_t)tok * 32 + m] * w;
    float im = fiw[(size_t)tok * 32 + m] * w;
    float c = wsh[32 + m], s = wsh[64 + m];
    ffs[tk][m]      = re * c - im * s;   // real_rot
    ffs[tk][32 + m] = re * s + im * c;   // imag_rot
  }
  __syncthreads();
  for (int p = 0; p < 4; ++p){
    int dd = p * 256 + tid;
    float bb = fteb[dd];
    float a0 = bb, a1 = bb, a2 = bb, a3 = bb;
    #pragma unroll 8
    for (int k = 0; k < 64; ++k){
      float wv = ftew[k * 1024 + dd];
      a0 += ffs[0][k] * wv; a1 += ffs[1][k] * wv;
      a2 += ffs[2][k] * wv; a3 += ffs[3][k] * wv;
    }
    xs[0][dd] = a0; xs[1][dd] = a1; xs[2][dd] = a2; xs[3][dd] = a3;
  }
  __syncthreads();
  for (int p = 0; p < 4; ++p){
    int dd = p * 256 + tid, dm = (dd + 1023) & 1023;  // roll(+1): x[d-1 mod D]
    #pragma unroll
    for (int tk = 0; tk < 4; ++tk){
      float pp = posph[(size_t)(t0 + tk) * 1024 + dd];
      float sp, cp; sincosf(pp, &sp, &cp);
      xout[((size_t)b * 4096 + t0 + tk) * 1024 + dd] = xs[tk][dd] * cp + xs[tk][dm] * sp;
    }
  }
}

// ---------------- kernel B: truncated forward DFT (32 modes) ----------------
// grid 128 (= B * 32 d-chunks of 32), block 512: 32 d x 16 groups x 2 modes
__global__ __launch_bounds__(512) void kernelB(const float* __restrict__ xin,
    const float* __restrict__ ctab, const float* __restrict__ stab,
    float* __restrict__ Xr, float* __restrict__ Xi){
  __shared__ float xsh[64][32];
  __shared__ float csh[32][64];
  __shared__ float ssh[32][64];
  int tid = threadIdx.x;
  int b = blockIdx.x >> 5, d0 = (blockIdx.x & 31) * 32;
  int dl = tid & 31, g = tid >> 5;     // g in 0..15
  int m0 = g * 2, m1 = m0 + 1;
  float ar0 = 0, ai0 = 0, ar1 = 0, ai1 = 0;
  for (int t0 = 0; t0 < 4096; t0 += 64){
    for (int i = 0; i < 4; ++i){
      int idx = i * 512 + tid; int tt = idx >> 5, dd = idx & 31;
      xsh[tt][dd] = xin[((size_t)b * 4096 + t0 + tt) * 1024 + d0 + dd];
    }
    for (int i = 0; i < 4; ++i){
      int idx = i * 512 + tid; int mm = idx >> 6, tt = idx & 63;
      csh[mm][tt] = ctab[mm * 4096 + t0 + tt];
      ssh[mm][tt] = stab[mm * 4096 + t0 + tt];
    }
    __syncthreads();
    #pragma unroll 8
    for (int tt = 0; tt < 64; ++tt){
      float xv = xsh[tt][dl];
      ar0 += xv * csh[m0][tt]; ai0 -= xv * ssh[m0][tt];
      ar1 += xv * csh[m1][tt]; ai1 -= xv * ssh[m1][tt];
    }
    __syncthreads();
  }
  const float inv = 0.015625f;  // 1/sqrt(4096), ortho norm
  int d = d0 + dl, n = d >> 7, j = d & 127;
  size_t base = (((size_t)b * 8 + n) * 32) * 128 + j;
  Xr[base + (size_t)m0 * 128] = ar0 * inv; Xi[base + (size_t)m0 * 128] = ai0 * inv;
  Xr[base + (size_t)m1 * 128] = ar1 * inv; Xi[base + (size_t)m1 * 128] = ai1 * inv;
}

// ---------------- kernel C: per-(n,m) complex 128x128 matmul + softshrink ----------------
// grid 256 (= 8 blocks * 32 modes), block 128 (thread = output row i)
__global__ __launch_bounds__(128) void kernelC(const float* __restrict__ Xr, const float* __restrict__ Xi,
    const float* __restrict__ awr, const float* __restrict__ awi,
    float* __restrict__ Or, float* __restrict__ Oi){
  __shared__ float xr_s[4][128], xi_s[4][128];
  int nm = blockIdx.x; int n = nm >> 5, m = nm & 31;
  int i = threadIdx.x;
  for (int b = 0; b < 4; ++b){
    size_t src = (((size_t)b * 8 + n) * 32 + m) * 128 + i;
    xr_s[b][i] = Xr[src]; xi_s[b][i] = Xi[src];
  }
  __syncthreads();
  float accr[4] = {0,0,0,0}, acci[4] = {0,0,0,0};
  size_t wb = (((size_t)n * 32 + m) * 128 + i) * 128;
  for (int j = 0; j < 128; ++j){
    float wr = awr[wb + j], wi = awi[wb + j];
    #pragma unroll
    for (int b = 0; b < 4; ++b){
      accr[b] += wr * xr_s[b][j] - wi * xi_s[b][j];
      acci[b] += wr * xi_s[b][j] + wi * xr_s[b][j];
    }
  }
  #pragma unroll
  for (int b = 0; b < 4; ++b){
    float vr = accr[b], vi = acci[b];
    vr = vr > 0.01f ? vr - 0.01f : (vr < -0.01f ? vr + 0.01f : 0.0f);
    vi = vi > 0.01f ? vi - 0.01f : (vi < -0.01f ? vi + 0.01f : 0.0f);
    size_t dst = ((size_t)b * 32 + m) * 1024 + n * 128 + i;  // [b][m][d] layout
    Or[dst] = vr; Oi[dst] = vi;
  }
}

// ---------------- kernel D: inverse truncated DFT + residual + LN1 -> bf16 ----------------
// grid 16384 (= B*T), block 256
__global__ __launch_bounds__(256) void kernelD(const float* __restrict__ Or, const float* __restrict__ Oi,
    const float* __restrict__ ctab, const float* __restrict__ stab,
    const float* __restrict__ residual, const float* __restrict__ g1,
    const float* __restrict__ b1v, short* __restrict__ xln1){
  int blk = blockIdx.x;
  int b = blk >> 12, t = blk & 4095;
  int tid = threadIdx.x;
  __shared__ float cts[32], sts[32];
  __shared__ float rs[4], rq[4];
  if (tid < 32){
    float f = (tid == 0 ? 1.0f : 2.0f) * 0.015625f;  // irfft ortho: (1/sqrt(T)) * (1 or 2)
    cts[tid] = ctab[tid * 4096 + t] * f;
    sts[tid] = stab[tid * 4096 + t] * f;             // sts[0] = 0 -> imag of mode 0 ignored
  }
  __syncthreads();
  float vals[4]; float sum = 0.0f, sq = 0.0f;
  for (int p = 0; p < 4; ++p){
    int d = p * 256 + tid;
    size_t base = ((size_t)b * 32) * 1024 + d;
    float s = 0.0f;
    #pragma unroll 8
    for (int m = 0; m < 32; ++m){
      s += cts[m] * Or[base + (size_t)m * 1024] - sts[m] * Oi[base + (size_t)m * 1024];
    }
    float v = s + residual[((size_t)b * 4096 + t) * 1024 + d];
    vals[p] = v; sum += v; sq += v * v;
  }
  for (int off = 32; off; off >>= 1){ sum += __shfl_down(sum, off); sq += __shfl_down(sq, off); }
  int lane = tid & 63, w = tid >> 6;
  if (lane == 0){ rs[w] = sum; rq[w] = sq; }
  __syncthreads();
  sum = rs[0] + rs[1] + rs[2] + rs[3]; sq = rq[0] + rq[1] + rq[2] + rq[3];
  float mu = sum * (1.0f / 1024.0f);
  float var = sq * (1.0f / 1024.0f) - mu * mu;
  float sc = rsqrtf(var + 1e-5f);
  for (int p = 0; p < 4; ++p){
    int d = p * 256 + tid;
    float y = (vals[p] - mu) * sc * g1[d] + b1v[d];
    xln1[((size_t)b * 4096 + t) * 1024 + d] = f2bf(y);
  }
}

// ---------------- bf16 MFMA GEMM, B^T layout: C[row,col] = sum_k A[row,k]*BT[col,k] ----------------
// 128x128 tile, 4 waves (2x2), each wave 64x64 (4x4 frags of 16x16x32), BK=64, single-buffered.
// EPI==0: += bias, exact gelu, store bf16 to Hout (chunk-local rows, stride N)
// EPI==1: += bias + bf16 residual (abs rows), store f32 to Fout (stride 1024)
template<int EPI>
__global__ __launch_bounds__(256) void gemm_bt_k(const short* __restrict__ A,
    const short* __restrict__ BT, const float* __restrict__ bias,
    const short* __restrict__ resid, short* __restrict__ Hout,
    float* __restrict__ Fout, int K, int N, long row0_abs){
  __shared__ short As[128][72];   // pad 64 -> 72 (row stride 144B: 2-way bank alias = free)
  __shared__ short Bs[128][72];
  int tid = threadIdx.x;
  long arow0 = (long)blockIdx.x * 128;
  long bcol0 = (long)blockIdx.y * 128;
  int lane = tid & 63, wv = tid >> 6;
  int wr = wv >> 1, wc = wv & 1;
  int lr = lane & 15, lk = (lane >> 4) * 8;
  f32x4 acc[4][4] = {};
  for (int k0 = 0; k0 < K; k0 += 64){
    #pragma unroll
    for (int u = 0; u < 4; ++u){
      int idx = u * 256 + tid;
      int r = idx >> 3, kc = (idx & 7) * 8;
      *(s16x8*)&As[r][kc] = *(const s16x8*)&A [(arow0 + r) * (long)K + k0 + kc];
      *(s16x8*)&Bs[r][kc] = *(const s16x8*)&BT[(bcol0 + r) * (long)K + k0 + kc];
    }
    __syncthreads();
    #pragma unroll
    for (int ks = 0; ks < 2; ++ks){
      int ko = ks * 32 + lk;
      s16x8 af[4], bfv[4];
      #pragma unroll
      for (int mi = 0; mi < 4; ++mi) af[mi]  = *(const s16x8*)&As[wr * 64 + mi * 16 + lr][ko];
      #pragma unroll
      for (int ni = 0; ni < 4; ++ni) bfv[ni] = *(const s16x8*)&Bs[wc * 64 + ni * 16 + lr][ko];
      #pragma unroll
      for (int mi = 0; mi < 4; ++mi)
        #pragma unroll
        for (int ni = 0; ni < 4; ++ni)
          acc[mi][ni] = __builtin_amdgcn_mfma_f32_16x16x32_bf16(af[mi], bfv[ni], acc[mi][ni], 0, 0, 0);
    }
    __syncthreads();
  }
  int rbase = (lane >> 4) * 4;   // C/D layout: col = lane&15, row = (lane>>4)*4 + reg
  #pragma unroll
  for (int mi = 0; mi < 4; ++mi){
    #pragma unroll
    for (int ni = 0; ni < 4; ++ni){
      int cl = (int)bcol0 + wc * 64 + ni * 16 + lr;
      float bv = bias[cl];
      #pragma unroll
      for (int i = 0; i < 4; ++i){
        long rl = arow0 + wr * 64 + mi * 16 + rbase + i;
        float v = acc[mi][ni][i] + bv;
        if (EPI == 0){
          float gg = 0.5f * v * (1.0f + erff(v * 0.70710678118f));  // exact gelu
          Hout[rl * (long)N + cl] = f2bf(gg);
        } else {
          float rr = bf2f(resid[(row0_abs + rl) * 1024 + cl]);
          Fout[(row0_abs + rl) * 1024 + cl] = v + rr;
        }
      }
    }
  }
}

// ---------------- LN2 in-place on f32 out ----------------
__global__ __launch_bounds__(256) void ln2_k(float* __restrict__ out,
    const float* __restrict__ g, const float* __restrict__ bb){
  size_t row = blockIdx.x;
  float* p = out + row * 1024;
  int tid = threadIdx.x;
  float v[4]; float sum = 0.0f, sq = 0.0f;
  for (int i = 0; i < 4; ++i){ float x = p[i * 256 + tid]; v[i] = x; sum += x; sq += x * x; }
  for (int off = 32; off; off >>= 1){ sum += __shfl_down(sum, off); sq += __shfl_down(sq, off); }
  __shared__ float rs[4], rq[4];
  int lane = tid & 63, w = tid >> 6;
  if (lane == 0){ rs[w] = sum; rq[w] = sq; }
  __syncthreads();
  sum = rs[0] + rs[1] + rs[2] + rs[3]; sq = rq[0] + rq[1] + rq[2] + rq[3];
  float mu = sum * (1.0f / 1024.0f);
  float var = sq * (1.0f / 1024.0f) - mu * mu;
  float sc = rsqrtf(var + 1e-5f);
  for (int i = 0; i < 4; ++i){
    int d = i * 256 + tid;
    p[d] = (v[i] - mu) * sc * g[d] + bb[d];
  }
}

// ---------------- launch ----------------
extern "C" void kernel_launch(void* const* d_in, const int* in_sizes, int n_in,
                              void* d_out, int out_size, void* d_ws, size_t ws_size,
                              hipStream_t stream){
  (void)in_sizes; (void)n_in; (void)out_size; (void)ws_size;
  const int*   tokens = (const int*)d_in[0];
  const float* frw  = (const float*)d_in[1];
  const float* fiw  = (const float*)d_in[2];
  const float* mw   = (const float*)d_in[3];
  const float* po   = (const float*)d_in[4];
  const float* ftew = (const float*)d_in[5];
  const float* fteb = (const float*)d_in[6];
  const float* posph= (const float*)d_in[7];
  const float* awr  = (const float*)d_in[8];
  const float* awi  = (const float*)d_in[9];
  const float* ln1g = (const float*)d_in[10];
  const float* ln1b = (const float*)d_in[11];
  const float* w1   = (const float*)d_in[12];
  const float* b1   = (const float*)d_in[13];
  const float* w2   = (const float*)d_in[14];
  const float* b2   = (const float*)d_in[15];
  const float* ln2g = (const float*)d_in[16];
  const float* ln2b = (const float*)d_in[17];
  float* out = (float*)d_out;

  char* ws = (char*)d_ws;
  size_t o = 0;
  float* residual = (float*)(ws + o); o += (size_t)16384 * 1024 * 4;  // 67.1 MB
  short* xln1     = (short*)(ws + o); o += (size_t)16384 * 1024 * 2;  // 33.6 MB
  short* w1b      = (short*)(ws + o); o += (size_t)4096 * 1024 * 2;   //  8.4 MB (W1^T bf16, 4096x1024)
  short* w2b      = (short*)(ws + o); o += (size_t)4096 * 1024 * 2;   //  8.4 MB (W2^T bf16, 1024x4096)
  float* Xr       = (float*)(ws + o); o += 524288;
  float* Xi       = (float*)(ws + o); o += 524288;
  float* Or       = (float*)(ws + o); o += 524288;
  float* Oi       = (float*)(ws + o); o += 524288;
  float* ctab     = (float*)(ws + o); o += 524288;
  float* stab     = (float*)(ws + o); o += 524288;
  float* wcs      = (float*)(ws + o); o += 512;
  short* hbuf     = (short*)(ws + o); o += (size_t)4096 * 4096 * 2;   // 33.6 MB (h chunk)

  prep_wcs_k<<<1, 64, 0, stream>>>(mw, po, wcs);
  prep_tab_k<<<512, 256, 0, stream>>>(ctab, stab);
  transpose_bf16_k<<<dim3(64, 16), 256, 0, stream>>>(w1, w1b, 1024, 4096);
  transpose_bf16_k<<<dim3(16, 64), 256, 0, stream>>>(w2, w2b, 4096, 1024);

  kernelA<<<4096, 256, 0, stream>>>(tokens, frw, fiw, wcs, ftew, fteb, posph, residual);
  kernelB<<<128, 512, 0, stream>>>(residual, ctab, stab, Xr, Xi);
  kernelC<<<256, 128, 0, stream>>>(Xr, Xi, awr, awi, Or, Oi);
  kernelD<<<16384, 256, 0, stream>>>(Or, Oi, ctab, stab, residual, ln1g, ln1b, xln1);

  for (int c = 0; c < 4; ++c){
    long row0 = (long)c * 4096;
    gemm_bt_k<0><<<dim3(32, 32), 256, 0, stream>>>(xln1 + row0 * 1024, w1b, b1,
                                                   nullptr, hbuf, nullptr, 1024, 4096, 0);
    gemm_bt_k<1><<<dim3(32, 8), 256, 0, stream>>>(hbuf, w2b, b2,
                                                  xln1, nullptr, out, 4096, 1024, row0);
  }
  ln2_k<<<16384, 256, 0, stream>>>(out, ln2g, ln2b);
}

// Round 2
// 728.384 us; speedup vs baseline: 1.3991x; 1.3991x over previous
//
#include <hip/hip_runtime.h>

// WaveInputEncoder on MI355X — round 2.
// Changes vs r1: kernelB t-split + rotation recurrence (no tables); GEMM uses
// global_load_lds(16B) m97-style staging, M-chunks of 8192 (hbuf aliases residual);
// kernelD split into tiled irfft (D1, in-place on residual) + LN1 (D2, vectorized);
// kernelA uses polynomial sin/cos for the tiny positional phases.

typedef __attribute__((ext_vector_type(8))) short s16x8;
typedef __attribute__((ext_vector_type(4))) short s16x4;
typedef __attribute__((ext_vector_type(4))) float f32x4;

__device__ __forceinline__ short f2bf(float x){
  unsigned u = __float_as_uint(x);
  unsigned r = (u + 0x7fffu + ((u >> 16) & 1u)) >> 16;   // RNE
  return (short)r;
}
__device__ __forceinline__ float bf2f(short x){
  return __uint_as_float(((unsigned)(unsigned short)x) << 16);
}
__device__ __forceinline__ void gload16(const void* g, void* l){
  __builtin_amdgcn_global_load_lds((const __attribute__((address_space(1))) void*)g,
                                   (__attribute__((address_space(3))) void*)l, 16, 0, 0);
}

// ---------------- prep kernels ----------------
__global__ void prep_wcs_k(const float* __restrict__ mw, const float* __restrict__ po,
                           float* __restrict__ wcs){
  int i = threadIdx.x;
  if (i < 32){
    wcs[i]      = log1pf(expf(mw[i]));  // softplus
    wcs[32 + i] = cosf(po[i]);
    wcs[64 + i] = sinf(po[i]);
  }
}

__global__ __launch_bounds__(256) void prep_tab_k(float* __restrict__ ctab, float* __restrict__ stab){
  int idx = blockIdx.x * 256 + threadIdx.x;      // idx = m*4096 + t
  int m = idx >> 12, t = idx & 4095;
  int r = (m * t) & 4095;                        // exact angle reduction
  float ang = (float)r * 1.5339807878856412e-3f; // 2*pi/4096
  float s, c; sincosf(ang, &s, &c);
  ctab[idx] = c; stab[idx] = s;
}

// transpose fp32 (R x C) -> bf16 (C x R), 64x64 LDS tiles
__global__ __launch_bounds__(256) void transpose_bf16_k(const float* __restrict__ src,
                                                        short* __restrict__ dst,
                                                        int R, int C){
  __shared__ float tile[64][65];
  int c0 = blockIdx.x * 64, r0 = blockIdx.y * 64;
  for (int i = 0; i < 16; ++i){
    int idx = i * 256 + threadIdx.x;
    int rr = idx >> 6, cc = idx & 63;
    tile[rr][cc] = src[(size_t)(r0 + rr) * C + c0 + cc];
  }
  __syncthreads();
  for (int i = 0; i < 16; ++i){
    int idx = i * 256 + threadIdx.x;
    int cc = idx >> 6, rr = idx & 63;
    dst[(size_t)(c0 + cc) * R + r0 + rr] = f2bf(tile[rr][cc]);
  }
}

// ---------------- kernel A: embed + rotate + FTE + positional phase ----------------
__global__ __launch_bounds__(256) void kernelA(const int* __restrict__ tokens,
    const float* __restrict__ frw, const float* __restrict__ fiw,
    const float* __restrict__ wcs, const float* __restrict__ ftew,
    const float* __restrict__ fteb, const float* __restrict__ posph,
    float* __restrict__ xout){
  __shared__ float ffs[4][64];
  __shared__ float xs[4][1024];
  __shared__ float wsh[96];
  int tid = threadIdx.x;
  int b = blockIdx.x >> 10, t0 = (blockIdx.x & 1023) * 4;
  if (tid < 96) wsh[tid] = wcs[tid];
  __syncthreads();
  if (tid < 128){
    int tk = tid >> 5, m = tid & 31;
    int tok = tokens[b * 4096 + t0 + tk];
    float w = wsh[m];
    float re = frw[(size_t)tok * 32 + m] * w;
    float im = fiw[(size_t)tok * 32 + m] * w;
    float c = wsh[32 + m], s = wsh[64 + m];
    ffs[tk][m]      = re * c - im * s;
    ffs[tk][32 + m] = re * s + im * c;
  }
  __syncthreads();
  for (int p = 0; p < 4; ++p){
    int dd = p * 256 + tid;
    float bb = fteb[dd];
    float a0 = bb, a1 = bb, a2 = bb, a3 = bb;
    #pragma unroll 8
    for (int k = 0; k < 64; ++k){
      float wv = ftew[k * 1024 + dd];
      a0 += ffs[0][k] * wv; a1 += ffs[1][k] * wv;
      a2 += ffs[2][k] * wv; a3 += ffs[3][k] * wv;
    }
    xs[0][dd] = a0; xs[1][dd] = a1; xs[2][dd] = a2; xs[3][dd] = a3;
  }
  __syncthreads();
  for (int p = 0; p < 4; ++p){
    int dd = p * 256 + tid, dm = (dd + 1023) & 1023;  // roll(+1): x[d-1 mod D]
    #pragma unroll
    for (int tk = 0; tk < 4; ++tk){
      float pp = posph[(size_t)(t0 + tk) * 1024 + dd];
      float p2 = pp * pp;
      float sp = pp * (1.0f - p2 * (1.0f/6.0f) + p2 * p2 * (1.0f/120.0f));
      float cp = 1.0f - p2 * 0.5f + p2 * p2 * (1.0f/24.0f);
      xout[((size_t)b * 4096 + t0 + tk) * 1024 + dd] = xs[tk][dd] * cp + xs[tk][dm] * sp;
    }
  }
}

// ---------------- kernel B: truncated forward DFT via rotation recurrence ----------------
// grid 1024 = b(4) x dchunk(32, 32 d each) x tchunk(8, 512 t each); block 256 = dg(8)*m(32)
__global__ __launch_bounds__(256) void kernelB2(const float* __restrict__ xin,
    float* __restrict__ Pr, float* __restrict__ Pi){
  __shared__ float xsh[64][32];
  int tid = threadIdx.x;
  int bx = blockIdx.x;
  int b = bx >> 8, dch = (bx >> 3) & 31, tc = bx & 7;
  int d0 = dch * 32;
  int t_start = tc * 512;
  int dg = tid >> 5, m = tid & 31;
  const float TPN = 1.5339807878856412e-3f;  // 2*pi/4096
  int r0 = (m * t_start) & 4095;
  float cw, sw; sincosf(-(float)r0 * TPN, &sw, &cw);   // w = e^{-i*2pi*m*t/T}
  float cs, ss; sincosf(-(float)m * TPN, &ss, &cs);    // per-step rotation
  float ar[4] = {0,0,0,0}, ai[4] = {0,0,0,0};
  for (int t0 = t_start; t0 < t_start + 512; t0 += 64){
    __syncthreads();
    #pragma unroll
    for (int i = 0; i < 2; ++i){
      int unit = i * 256 + tid;
      int tt = unit >> 3, du = (unit & 7) * 4;
      *(f32x4*)&xsh[tt][du] = *(const f32x4*)&xin[((size_t)b * 4096 + t0 + tt) * 1024 + d0 + du];
    }
    __syncthreads();
    #pragma unroll 4
    for (int tt = 0; tt < 64; ++tt){
      f32x4 xv = *(const f32x4*)&xsh[tt][dg * 4];
      #pragma unroll
      for (int j = 0; j < 4; ++j){ ar[j] += xv[j] * cw; ai[j] += xv[j] * sw; }
      float cn = cw * cs - sw * ss;
      sw = cw * ss + sw * cs; cw = cn;
    }
  }
  #pragma unroll
  for (int j = 0; j < 4; ++j){
    int d = d0 + dg * 4 + j;
    size_t idx = (((size_t)tc * 4 + b) * 1024 + d) * 32 + m;
    Pr[idx] = ar[j]; Pi[idx] = ai[j];
  }
}

// sum 8 t-chunk partials, scale by 1/64, reorder to [b][n][m][j] for kernelC
__global__ __launch_bounds__(256) void reduceB_k(const float* __restrict__ Pr,
    const float* __restrict__ Pi, float* __restrict__ Xr, float* __restrict__ Xi){
  int lin = blockIdx.x * 256 + threadIdx.x;   // 131072
  int m = lin & 31, d = (lin >> 5) & 1023, b = lin >> 15;
  float sr = 0.0f, si = 0.0f;
  for (int tc = 0; tc < 8; ++tc){
    size_t idx = (((size_t)tc * 4 + b) * 1024 + d) * 32 + m;
    sr += Pr[idx]; si += Pi[idx];
  }
  int n = d >> 7, jj = d & 127;
  size_t o = (((size_t)b * 8 + n) * 32 + m) * 128 + jj;
  Xr[o] = sr * 0.015625f; Xi[o] = si * 0.015625f;
}

// ---------------- kernel C: per-(n,m) complex 128x128 matmul + softshrink ----------------
__global__ __launch_bounds__(128) void kernelC(const float* __restrict__ Xr, const float* __restrict__ Xi,
    const float* __restrict__ awr, const float* __restrict__ awi,
    float* __restrict__ Or, float* __restrict__ Oi){
  __shared__ float xr_s[4][128], xi_s[4][128];
  int nm = blockIdx.x; int n = nm >> 5, m = nm & 31;
  int i = threadIdx.x;
  for (int b = 0; b < 4; ++b){
    size_t src = (((size_t)b * 8 + n) * 32 + m) * 128 + i;
    xr_s[b][i] = Xr[src]; xi_s[b][i] = Xi[src];
  }
  __syncthreads();
  float accr[4] = {0,0,0,0}, acci[4] = {0,0,0,0};
  size_t wb = (((size_t)n * 32 + m) * 128 + i) * 128;
  for (int j = 0; j < 128; ++j){
    float wr = awr[wb + j], wi = awi[wb + j];
    #pragma unroll
    for (int b = 0; b < 4; ++b){
      accr[b] += wr * xr_s[b][j] - wi * xi_s[b][j];
      acci[b] += wr * xi_s[b][j] + wi * xr_s[b][j];
    }
  }
  #pragma unroll
  for (int b = 0; b < 4; ++b){
    float vr = accr[b], vi = acci[b];
    vr = vr > 0.01f ? vr - 0.01f : (vr < -0.01f ? vr + 0.01f : 0.0f);
    vi = vi > 0.01f ? vi - 0.01f : (vi < -0.01f ? vi + 0.01f : 0.0f);
    size_t dst = ((size_t)b * 32 + m) * 1024 + n * 128 + i;  // [b][m][d]
    Or[dst] = vr; Oi[dst] = vi;
  }
}

// ---------------- kernel D1: tiled inverse DFT + residual (in-place on y==residual) ----------------
// grid 512 = b(4) x tgroup(128, 32 t each); block 256 = t2(16)*dl(16)
__global__ __launch_bounds__(256) void kernelD1(const float* __restrict__ Or, const float* __restrict__ Oi,
    const float* __restrict__ ctab, const float* __restrict__ stab, float* __restrict__ y){
  __shared__ float cts[32][32], sts[32][32];
  __shared__ float Ors[32][256], Ois[32][256];
  int tid = threadIdx.x;
  int b = blockIdx.x >> 7, t0 = (blockIdx.x & 127) * 32;
  for (int i = 0; i < 4; ++i){
    int lin = i * 256 + tid;  // 1024
    int m = lin >> 5, tt = lin & 31;
    float f = (m == 0 ? 1.0f : 2.0f) * 0.015625f;   // irfft ortho scale
    cts[m][tt] = ctab[m * 4096 + t0 + tt] * f;
    sts[m][tt] = stab[m * 4096 + t0 + tt] * f;      // sts[0]=0 -> mode-0 imag ignored
  }
  int t2 = tid >> 4, dl = tid & 15;
  for (int c = 0; c < 4; ++c){
    __syncthreads();
    for (int i = 0; i < 32; ++i){
      int lin = i * 256 + tid; // 8192
      int m = lin >> 8, dd = lin & 255;
      size_t src = ((size_t)b * 32 + m) * 1024 + c * 256 + dd;
      Ors[m][dd] = Or[src]; Ois[m][dd] = Oi[src];
    }
    __syncthreads();
    float acc[2][16];
    #pragma unroll
    for (int ti = 0; ti < 2; ++ti)
      #pragma unroll
      for (int j = 0; j < 16; ++j) acc[ti][j] = 0.0f;
    for (int m = 0; m < 32; ++m){
      float c0 = cts[m][t2 * 2], c1 = cts[m][t2 * 2 + 1];
      float s0 = sts[m][t2 * 2], s1 = sts[m][t2 * 2 + 1];
      #pragma unroll
      for (int j = 0; j < 16; ++j){
        float orv = Ors[m][dl + 16 * j], oiv = Ois[m][dl + 16 * j];
        acc[0][j] += c0 * orv - s0 * oiv;
        acc[1][j] += c1 * orv - s1 * oiv;
      }
    }
    #pragma unroll
    for (int ti = 0; ti < 2; ++ti){
      size_t rowb = ((size_t)b * 4096 + t0 + t2 * 2 + ti) * 1024 + c * 256;
      #pragma unroll
      for (int j = 0; j < 16; ++j)
        y[rowb + dl + 16 * j] += acc[ti][j];   // in-place: y holds residual
    }
  }
}

// ---------------- LN1: y (f32) -> xln1 (bf16) ----------------
__global__ __launch_bounds__(256) void ln1_k(const float* __restrict__ y,
    const float* __restrict__ g, const float* __restrict__ bb, short* __restrict__ xln){
  size_t row = blockIdx.x;
  int tid = threadIdx.x;
  f32x4 v = *(const f32x4*)(y + row * 1024 + tid * 4);
  float sum = v[0] + v[1] + v[2] + v[3];
  float sq  = v[0]*v[0] + v[1]*v[1] + v[2]*v[2] + v[3]*v[3];
  for (int off = 32; off; off >>= 1){ sum += __shfl_down(sum, off); sq += __shfl_down(sq, off); }
  __shared__ float rs[4], rq[4];
  int lane = tid & 63, w = tid >> 6;
  if (lane == 0){ rs[w] = sum; rq[w] = sq; }
  __syncthreads();
  sum = rs[0] + rs[1] + rs[2] + rs[3]; sq = rq[0] + rq[1] + rq[2] + rq[3];
  float mu = sum * (1.0f / 1024.0f);
  float var = sq * (1.0f / 1024.0f) - mu * mu;
  float sc = rsqrtf(var + 1e-5f);
  s16x4 o;
  #pragma unroll
  for (int j = 0; j < 4; ++j){
    int d = tid * 4 + j;
    o[j] = f2bf((v[j] - mu) * sc * g[d] + bb[d]);
  }
  *(s16x4*)(xln + row * 1024 + tid * 4) = o;
}

// ---------------- bf16 MFMA GEMM, m97-style global_load_lds staging ----------------
// 128x128 tile, 4 waves (2x2), 64x64/wave, BK=64, linear LDS, async global->LDS 16B.
template<int EPI>
__global__ __launch_bounds__(256) void gemm_bt_k(const short* __restrict__ A,
    const short* __restrict__ BT, const float* __restrict__ bias,
    const short* __restrict__ resid, short* __restrict__ Hout,
    float* __restrict__ Fout, int K, int N, long row0_abs){
  __shared__ __align__(16) short As[128 * 64];
  __shared__ __align__(16) short Bs[128 * 64];
  int tid = threadIdx.x;
  long arow0 = (long)blockIdx.x * 128;
  long bcol0 = (long)blockIdx.y * 128;
  int lane = tid & 63, wv = tid >> 6;
  int wr = wv >> 1, wc = wv & 1;
  int lr = lane & 15, lk = (lane >> 4) * 8;
  f32x4 acc[4][4] = {};
  for (int k0 = 0; k0 < K; k0 += 64){
    #pragma unroll
    for (int u = 0; u < 4; ++u){
      int idx = u * 256 + tid;
      long r = idx >> 3; int un = idx & 7;
      int ldsoff = (u * 256 + (wv << 6)) << 3;   // shorts; lane slot = +lane*8 (HW)
      gload16(A  + (arow0 + r) * (long)K + k0 + un * 8, As + ldsoff);
      gload16(BT + (bcol0 + r) * (long)K + k0 + un * 8, Bs + ldsoff);
    }
    __syncthreads();   // drains vmcnt before barrier
    #pragma unroll
    for (int ks = 0; ks < 2; ++ks){
      int ko = ks * 32 + lk;
      s16x8 af[4], bfv[4];
      #pragma unroll
      for (int mi = 0; mi < 4; ++mi) af[mi]  = *(const s16x8*)&As[(wr * 64 + mi * 16 + lr) * 64 + ko];
      #pragma unroll
      for (int ni = 0; ni < 4; ++ni) bfv[ni] = *(const s16x8*)&Bs[(wc * 64 + ni * 16 + lr) * 64 + ko];
      #pragma unroll
      for (int mi = 0; mi < 4; ++mi)
        #pragma unroll
        for (int ni = 0; ni < 4; ++ni)
          acc[mi][ni] = __builtin_amdgcn_mfma_f32_16x16x32_bf16(af[mi], bfv[ni], acc[mi][ni], 0, 0, 0);
    }
    __syncthreads();
  }
  int rbase = (lane >> 4) * 4;   // C/D: col = lane&15, row = (lane>>4)*4 + reg
  #pragma unroll
  for (int mi = 0; mi < 4; ++mi){
    #pragma unroll
    for (int ni = 0; ni < 4; ++ni){
      int cl = (int)bcol0 + wc * 64 + ni * 16 + lr;
      float bv = bias[cl];
      #pragma unroll
      for (int i = 0; i < 4; ++i){
        long rl = arow0 + wr * 64 + mi * 16 + rbase + i;
        float v = acc[mi][ni][i] + bv;
        if (EPI == 0){
          float gg = 0.5f * v * (1.0f + erff(v * 0.70710678118f));  // exact gelu
          Hout[rl * (long)N + cl] = f2bf(gg);
        } else {
          float rr = bf2f(resid[(row0_abs + rl) * 1024 + cl]);
          Fout[(row0_abs + rl) * 1024 + cl] = v + rr;
        }
      }
    }
  }
}

// ---------------- LN2 in-place on f32 out ----------------
__global__ __launch_bounds__(256) void ln2_k(float* __restrict__ out,
    const float* __restrict__ g, const float* __restrict__ bb){
  size_t row = blockIdx.x;
  int tid = threadIdx.x;
  float* p = out + row * 1024;
  f32x4 v = *(const f32x4*)(p + tid * 4);
  float sum = v[0] + v[1] + v[2] + v[3];
  float sq  = v[0]*v[0] + v[1]*v[1] + v[2]*v[2] + v[3]*v[3];
  for (int off = 32; off; off >>= 1){ sum += __shfl_down(sum, off); sq += __shfl_down(sq, off); }
  __shared__ float rs[4], rq[4];
  int lane = tid & 63, w = tid >> 6;
  if (lane == 0){ rs[w] = sum; rq[w] = sq; }
  __syncthreads();
  sum = rs[0] + rs[1] + rs[2] + rs[3]; sq = rq[0] + rq[1] + rq[2] + rq[3];
  float mu = sum * (1.0f / 1024.0f);
  float var = sq * (1.0f / 1024.0f) - mu * mu;
  float sc = rsqrtf(var + 1e-5f);
  f32x4 o;
  #pragma unroll
  for (int j = 0; j < 4; ++j){
    int d = tid * 4 + j;
    o[j] = (v[j] - mu) * sc * g[d] + bb[d];
  }
  *(f32x4*)(p + tid * 4) = o;
}

// ---------------- launch ----------------
extern "C" void kernel_launch(void* const* d_in, const int* in_sizes, int n_in,
                              void* d_out, int out_size, void* d_ws, size_t ws_size,
                              hipStream_t stream){
  (void)in_sizes; (void)n_in; (void)out_size; (void)ws_size;
  const int*   tokens = (const int*)d_in[0];
  const float* frw  = (const float*)d_in[1];
  const float* fiw  = (const float*)d_in[2];
  const float* mw   = (const float*)d_in[3];
  const float* po   = (const float*)d_in[4];
  const float* ftew = (const float*)d_in[5];
  const float* fteb = (const float*)d_in[6];
  const float* posph= (const float*)d_in[7];
  const float* awr  = (const float*)d_in[8];
  const float* awi  = (const float*)d_in[9];
  const float* ln1g = (const float*)d_in[10];
  const float* ln1b = (const float*)d_in[11];
  const float* w1   = (const float*)d_in[12];
  const float* b1   = (const float*)d_in[13];
  const float* w2   = (const float*)d_in[14];
  const float* b2   = (const float*)d_in[15];
  const float* ln2g = (const float*)d_in[16];
  const float* ln2b = (const float*)d_in[17];
  float* out = (float*)d_out;

  char* ws = (char*)d_ws;
  size_t o = 0;
  float* residual = (float*)(ws + o); o += (size_t)16384 * 1024 * 4;  // 67.1 MB; later y; later hbuf
  short* xln1     = (short*)(ws + o); o += (size_t)16384 * 1024 * 2;  // 33.6 MB
  short* w1b      = (short*)(ws + o); o += (size_t)4096 * 1024 * 2;   //  8.4 MB
  short* w2b      = (short*)(ws + o); o += (size_t)4096 * 1024 * 2;   //  8.4 MB
  float* ctab     = (float*)(ws + o); o += 524288;
  float* stab     = (float*)(ws + o); o += 524288;
  float* Xr       = (float*)(ws + o); o += 524288;
  float* Xi       = (float*)(ws + o); o += 524288;
  float* Or       = (float*)(ws + o); o += 524288;
  float* Oi       = (float*)(ws + o); o += 524288;
  float* Pr       = (float*)(ws + o); o += (size_t)8 * 4 * 1024 * 32 * 4;  // 4.2 MB
  float* Pi       = (float*)(ws + o); o += (size_t)8 * 4 * 1024 * 32 * 4;  // 4.2 MB
  float* wcs      = (float*)(ws + o); o += 512;
  short* hbuf     = (short*)residual;   // 8192x4096 bf16 = 67.1 MB, aliases dead residual/y

  prep_wcs_k<<<1, 64, 0, stream>>>(mw, po, wcs);
  prep_tab_k<<<512, 256, 0, stream>>>(ctab, stab);
  transpose_bf16_k<<<dim3(64, 16), 256, 0, stream>>>(w1, w1b, 1024, 4096);
  transpose_bf16_k<<<dim3(16, 64), 256, 0, stream>>>(w2, w2b, 4096, 1024);

  kernelA<<<4096, 256, 0, stream>>>(tokens, frw, fiw, wcs, ftew, fteb, posph, residual);
  kernelB2<<<1024, 256, 0, stream>>>(residual, Pr, Pi);
  reduceB_k<<<512, 256, 0, stream>>>(Pr, Pi, Xr, Xi);
  kernelC<<<256, 128, 0, stream>>>(Xr, Xi, awr, awi, Or, Oi);
  kernelD1<<<512, 256, 0, stream>>>(Or, Oi, ctab, stab, residual);
  ln1_k<<<16384, 256, 0, stream>>>(residual, ln1g, ln1b, xln1);

  for (int c = 0; c < 2; ++c){
    long row0 = (long)c * 8192;
    gemm_bt_k<0><<<dim3(64, 32), 256, 0, stream>>>(xln1 + row0 * 1024, w1b, b1,
                                                   nullptr, hbuf, nullptr, 1024, 4096, 0);
    gemm_bt_k<1><<<dim3(64, 8), 256, 0, stream>>>(hbuf, w2b, b2,
                                                  xln1, nullptr, out, 4096, 1024, row0);
  }
  ln2_k<<<16384, 256, 0, stream>>>(out, ln2g, ln2b);
}

// Round 3
// 626.659 us; speedup vs baseline: 1.6262x; 1.1623x over previous
//
#include <hip/hip_runtime.h>

// WaveInputEncoder on MI355X — round 3.
// Changes vs r2: GEMMs rebuilt on the 256^2 deep-pipeline template:
//   8 waves, BK=64, double-buffered LDS (128KB), counted vmcnt(8/6) prefetch
//   (depth-2, never drained in-loop), raw s_barrier, T2 XOR slot-swizzle via
//   pre-swizzled global source (rule #21), setprio around MFMA, tanh-gelu.
// Everything else unchanged from r2.

typedef __attribute__((ext_vector_type(8))) short s16x8;
typedef __attribute__((ext_vector_type(4))) short s16x4;
typedef __attribute__((ext_vector_type(4))) float f32x4;

__device__ __forceinline__ short f2bf(float x){
  unsigned u = __float_as_uint(x);
  unsigned r = (u + 0x7fffu + ((u >> 16) & 1u)) >> 16;   // RNE
  return (short)r;
}
__device__ __forceinline__ float bf2f(short x){
  return __uint_as_float(((unsigned)(unsigned short)x) << 16);
}
__device__ __forceinline__ void gload16(const void* g, void* l){
  __builtin_amdgcn_global_load_lds((const __attribute__((address_space(1))) void*)g,
                                   (__attribute__((address_space(3))) void*)l, 16, 0, 0);
}
__device__ __forceinline__ float gelu_f(float v){
  // tanh-form gelu; max dev from exact erf-gelu ~3e-4 (below bf16 rounding)
  float u2 = v * (0.7978845608f + 0.0356774081f * v * v);
  float e = __expf(2.0f * u2);
  float th = 1.0f - 2.0f / (e + 1.0f);
  return 0.5f * v * (1.0f + th);
}

// ---------------- prep kernels ----------------
__global__ void prep_wcs_k(const float* __restrict__ mw, const float* __restrict__ po,
                           float* __restrict__ wcs){
  int i = threadIdx.x;
  if (i < 32){
    wcs[i]      = log1pf(expf(mw[i]));  // softplus
    wcs[32 + i] = cosf(po[i]);
    wcs[64 + i] = sinf(po[i]);
  }
}

__global__ __launch_bounds__(256) void prep_tab_k(float* __restrict__ ctab, float* __restrict__ stab){
  int idx = blockIdx.x * 256 + threadIdx.x;      // idx = m*4096 + t
  int m = idx >> 12, t = idx & 4095;
  int r = (m * t) & 4095;                        // exact angle reduction
  float ang = (float)r * 1.5339807878856412e-3f; // 2*pi/4096
  float s, c; sincosf(ang, &s, &c);
  ctab[idx] = c; stab[idx] = s;
}

// transpose fp32 (R x C) -> bf16 (C x R), 64x64 LDS tiles
__global__ __launch_bounds__(256) void transpose_bf16_k(const float* __restrict__ src,
                                                        short* __restrict__ dst,
                                                        int R, int C){
  __shared__ float tile[64][65];
  int c0 = blockIdx.x * 64, r0 = blockIdx.y * 64;
  for (int i = 0; i < 16; ++i){
    int idx = i * 256 + threadIdx.x;
    int rr = idx >> 6, cc = idx & 63;
    tile[rr][cc] = src[(size_t)(r0 + rr) * C + c0 + cc];
  }
  __syncthreads();
  for (int i = 0; i < 16; ++i){
    int idx = i * 256 + threadIdx.x;
    int cc = idx >> 6, rr = idx & 63;
    dst[(size_t)(c0 + cc) * R + r0 + rr] = f2bf(tile[rr][cc]);
  }
}

// ---------------- kernel A: embed + rotate + FTE + positional phase ----------------
__global__ __launch_bounds__(256) void kernelA(const int* __restrict__ tokens,
    const float* __restrict__ frw, const float* __restrict__ fiw,
    const float* __restrict__ wcs, const float* __restrict__ ftew,
    const float* __restrict__ fteb, const float* __restrict__ posph,
    float* __restrict__ xout){
  __shared__ float ffs[4][64];
  __shared__ float xs[4][1024];
  __shared__ float wsh[96];
  int tid = threadIdx.x;
  int b = blockIdx.x >> 10, t0 = (blockIdx.x & 1023) * 4;
  if (tid < 96) wsh[tid] = wcs[tid];
  __syncthreads();
  if (tid < 128){
    int tk = tid >> 5, m = tid & 31;
    int tok = tokens[b * 4096 + t0 + tk];
    float w = wsh[m];
    float re = frw[(size_t)tok * 32 + m] * w;
    float im = fiw[(size_t)tok * 32 + m] * w;
    float c = wsh[32 + m], s = wsh[64 + m];
    ffs[tk][m]      = re * c - im * s;
    ffs[tk][32 + m] = re * s + im * c;
  }
  __syncthreads();
  for (int p = 0; p < 4; ++p){
    int dd = p * 256 + tid;
    float bb = fteb[dd];
    float a0 = bb, a1 = bb, a2 = bb, a3 = bb;
    #pragma unroll 8
    for (int k = 0; k < 64; ++k){
      float wv = ftew[k * 1024 + dd];
      a0 += ffs[0][k] * wv; a1 += ffs[1][k] * wv;
      a2 += ffs[2][k] * wv; a3 += ffs[3][k] * wv;
    }
    xs[0][dd] = a0; xs[1][dd] = a1; xs[2][dd] = a2; xs[3][dd] = a3;
  }
  __syncthreads();
  for (int p = 0; p < 4; ++p){
    int dd = p * 256 + tid, dm = (dd + 1023) & 1023;  // roll(+1): x[d-1 mod D]
    #pragma unroll
    for (int tk = 0; tk < 4; ++tk){
      float pp = posph[(size_t)(t0 + tk) * 1024 + dd];
      float p2 = pp * pp;
      float sp = pp * (1.0f - p2 * (1.0f/6.0f) + p2 * p2 * (1.0f/120.0f));
      float cp = 1.0f - p2 * 0.5f + p2 * p2 * (1.0f/24.0f);
      xout[((size_t)b * 4096 + t0 + tk) * 1024 + dd] = xs[tk][dd] * cp + xs[tk][dm] * sp;
    }
  }
}

// ---------------- kernel B: truncated forward DFT via rotation recurrence ----------------
__global__ __launch_bounds__(256) void kernelB2(const float* __restrict__ xin,
    float* __restrict__ Pr, float* __restrict__ Pi){
  __shared__ float xsh[64][32];
  int tid = threadIdx.x;
  int bx = blockIdx.x;
  int b = bx >> 8, dch = (bx >> 3) & 31, tc = bx & 7;
  int d0 = dch * 32;
  int t_start = tc * 512;
  int dg = tid >> 5, m = tid & 31;
  const float TPN = 1.5339807878856412e-3f;  // 2*pi/4096
  int r0 = (m * t_start) & 4095;
  float cw, sw; sincosf(-(float)r0 * TPN, &sw, &cw);
  float cs, ss; sincosf(-(float)m * TPN, &ss, &cs);
  float ar[4] = {0,0,0,0}, ai[4] = {0,0,0,0};
  for (int t0 = t_start; t0 < t_start + 512; t0 += 64){
    __syncthreads();
    #pragma unroll
    for (int i = 0; i < 2; ++i){
      int unit = i * 256 + tid;
      int tt = unit >> 3, du = (unit & 7) * 4;
      *(f32x4*)&xsh[tt][du] = *(const f32x4*)&xin[((size_t)b * 4096 + t0 + tt) * 1024 + d0 + du];
    }
    __syncthreads();
    #pragma unroll 4
    for (int tt = 0; tt < 64; ++tt){
      f32x4 xv = *(const f32x4*)&xsh[tt][dg * 4];
      #pragma unroll
      for (int j = 0; j < 4; ++j){ ar[j] += xv[j] * cw; ai[j] += xv[j] * sw; }
      float cn = cw * cs - sw * ss;
      sw = cw * ss + sw * cs; cw = cn;
    }
  }
  #pragma unroll
  for (int j = 0; j < 4; ++j){
    int d = d0 + dg * 4 + j;
    size_t idx = (((size_t)tc * 4 + b) * 1024 + d) * 32 + m;
    Pr[idx] = ar[j]; Pi[idx] = ai[j];
  }
}

__global__ __launch_bounds__(256) void reduceB_k(const float* __restrict__ Pr,
    const float* __restrict__ Pi, float* __restrict__ Xr, float* __restrict__ Xi){
  int lin = blockIdx.x * 256 + threadIdx.x;   // 131072
  int m = lin & 31, d = (lin >> 5) & 1023, b = lin >> 15;
  float sr = 0.0f, si = 0.0f;
  for (int tc = 0; tc < 8; ++tc){
    size_t idx = (((size_t)tc * 4 + b) * 1024 + d) * 32 + m;
    sr += Pr[idx]; si += Pi[idx];
  }
  int n = d >> 7, jj = d & 127;
  size_t o = (((size_t)b * 8 + n) * 32 + m) * 128 + jj;
  Xr[o] = sr * 0.015625f; Xi[o] = si * 0.015625f;
}

// ---------------- kernel C ----------------
__global__ __launch_bounds__(128) void kernelC(const float* __restrict__ Xr, const float* __restrict__ Xi,
    const float* __restrict__ awr, const float* __restrict__ awi,
    float* __restrict__ Or, float* __restrict__ Oi){
  __shared__ float xr_s[4][128], xi_s[4][128];
  int nm = blockIdx.x; int n = nm >> 5, m = nm & 31;
  int i = threadIdx.x;
  for (int b = 0; b < 4; ++b){
    size_t src = (((size_t)b * 8 + n) * 32 + m) * 128 + i;
    xr_s[b][i] = Xr[src]; xi_s[b][i] = Xi[src];
  }
  __syncthreads();
  float accr[4] = {0,0,0,0}, acci[4] = {0,0,0,0};
  size_t wb = (((size_t)n * 32 + m) * 128 + i) * 128;
  for (int j = 0; j < 128; ++j){
    float wr = awr[wb + j], wi = awi[wb + j];
    #pragma unroll
    for (int b = 0; b < 4; ++b){
      accr[b] += wr * xr_s[b][j] - wi * xi_s[b][j];
      acci[b] += wr * xi_s[b][j] + wi * xr_s[b][j];
    }
  }
  #pragma unroll
  for (int b = 0; b < 4; ++b){
    float vr = accr[b], vi = acci[b];
    vr = vr > 0.01f ? vr - 0.01f : (vr < -0.01f ? vr + 0.01f : 0.0f);
    vi = vi > 0.01f ? vi - 0.01f : (vi < -0.01f ? vi + 0.01f : 0.0f);
    size_t dst = ((size_t)b * 32 + m) * 1024 + n * 128 + i;  // [b][m][d]
    Or[dst] = vr; Oi[dst] = vi;
  }
}

// ---------------- kernel D1: tiled inverse DFT + residual (in-place) ----------------
__global__ __launch_bounds__(256) void kernelD1(const float* __restrict__ Or, const float* __restrict__ Oi,
    const float* __restrict__ ctab, const float* __restrict__ stab, float* __restrict__ y){
  __shared__ float cts[32][32], sts[32][32];
  __shared__ float Ors[32][256], Ois[32][256];
  int tid = threadIdx.x;
  int b = blockIdx.x >> 7, t0 = (blockIdx.x & 127) * 32;
  for (int i = 0; i < 4; ++i){
    int lin = i * 256 + tid;
    int m = lin >> 5, tt = lin & 31;
    float f = (m == 0 ? 1.0f : 2.0f) * 0.015625f;
    cts[m][tt] = ctab[m * 4096 + t0 + tt] * f;
    sts[m][tt] = stab[m * 4096 + t0 + tt] * f;
  }
  int t2 = tid >> 4, dl = tid & 15;
  for (int c = 0; c < 4; ++c){
    __syncthreads();
    for (int i = 0; i < 32; ++i){
      int lin = i * 256 + tid;
      int m = lin >> 8, dd = lin & 255;
      size_t src = ((size_t)b * 32 + m) * 1024 + c * 256 + dd;
      Ors[m][dd] = Or[src]; Ois[m][dd] = Oi[src];
    }
    __syncthreads();
    float acc[2][16];
    #pragma unroll
    for (int ti = 0; ti < 2; ++ti)
      #pragma unroll
      for (int j = 0; j < 16; ++j) acc[ti][j] = 0.0f;
    for (int m = 0; m < 32; ++m){
      float c0 = cts[m][t2 * 2], c1 = cts[m][t2 * 2 + 1];
      float s0 = sts[m][t2 * 2], s1 = sts[m][t2 * 2 + 1];
      #pragma unroll
      for (int j = 0; j < 16; ++j){
        float orv = Ors[m][dl + 16 * j], oiv = Ois[m][dl + 16 * j];
        acc[0][j] += c0 * orv - s0 * oiv;
        acc[1][j] += c1 * orv - s1 * oiv;
      }
    }
    #pragma unroll
    for (int ti = 0; ti < 2; ++ti){
      size_t rowb = ((size_t)b * 4096 + t0 + t2 * 2 + ti) * 1024 + c * 256;
      #pragma unroll
      for (int j = 0; j < 16; ++j)
        y[rowb + dl + 16 * j] += acc[ti][j];
    }
  }
}

// ---------------- LN1: y (f32) -> xln1 (bf16) ----------------
__global__ __launch_bounds__(256) void ln1_k(const float* __restrict__ y,
    const float* __restrict__ g, const float* __restrict__ bb, short* __restrict__ xln){
  size_t row = blockIdx.x;
  int tid = threadIdx.x;
  f32x4 v = *(const f32x4*)(y + row * 1024 + tid * 4);
  float sum = v[0] + v[1] + v[2] + v[3];
  float sq  = v[0]*v[0] + v[1]*v[1] + v[2]*v[2] + v[3]*v[3];
  for (int off = 32; off; off >>= 1){ sum += __shfl_down(sum, off); sq += __shfl_down(sq, off); }
  __shared__ float rs[4], rq[4];
  int lane = tid & 63, w = tid >> 6;
  if (lane == 0){ rs[w] = sum; rq[w] = sq; }
  __syncthreads();
  sum = rs[0] + rs[1] + rs[2] + rs[3]; sq = rq[0] + rq[1] + rq[2] + rq[3];
  float mu = sum * (1.0f / 1024.0f);
  float var = sq * (1.0f / 1024.0f) - mu * mu;
  float sc = rsqrtf(var + 1e-5f);
  s16x4 o;
  #pragma unroll
  for (int j = 0; j < 4; ++j){
    int d = tid * 4 + j;
    o[j] = f2bf((v[j] - mu) * sc * g[d] + bb[d]);
  }
  *(s16x4*)(xln + row * 1024 + tid * 4) = o;
}

// ---------------- deep-pipeline 256-tile bf16 MFMA GEMM ----------------
// CFG 0: BM=256 BN=256, waves 2Mx4N, MI=8 NI=4, loads/tile A4+B4, steady vmcnt(8)
// CFG 1: BM=256 BN=128, waves 4Mx2N, MI=4 NI=4, loads/tile A4+B2, steady vmcnt(6)
// LDS layout per tile: [row][slot^(row&7)][8 shorts]  (T2 swizzle, rule #21:
//  linear global_load_lds dest + inverse-swizzled global source + swizzled read)
template<int CFG, int EPI>
__global__ __launch_bounds__(512, 2) void gemm8_k(const short* __restrict__ A,
    const short* __restrict__ BT, const float* __restrict__ bias,
    const short* __restrict__ resid, short* __restrict__ Hout,
    float* __restrict__ Fout, int K, int N, long row0_abs){
  constexpr int BROWS = (CFG == 0) ? 256 : 128;
  constexpr int MI = (CFG == 0) ? 8 : 4;
  constexpr int NI = 4;
  constexpr int AL = 4;
  constexpr int BL = (CFG == 0) ? 4 : 2;
  __shared__ __align__(16) short As[2][256 * 64];
  __shared__ __align__(16) short Bs[2][BROWS * 64];
  const int tid = threadIdx.x;
  const int lane = tid & 63, wv = tid >> 6;
  const int wr = (CFG == 0) ? (wv >> 2) : (wv >> 1);
  const int wc = (CFG == 0) ? (wv & 3) : (wv & 1);
  const long arow0 = (long)blockIdx.x * 256;
  const long bcol0 = (long)blockIdx.y * BROWS;
  const int NT = K >> 6;
  const int lr = lane & 15, lg = lane >> 4;

  auto STAGE = [&](int t){
    const long kof = (long)t * 64;
    short* abase = &As[t & 1][0];
    short* bbase = &Bs[t & 1][0];
    #pragma unroll
    for (int u = 0; u < AL; ++u){
      int idx = u * 512 + tid;
      int r = idx >> 3, sl = (idx & 7) ^ (r & 7);
      gload16(A + (arow0 + r) * (long)K + kof + sl * 8,
              abase + (u * 512 + wv * 64) * 8);
    }
    #pragma unroll
    for (int u = 0; u < BL; ++u){
      int idx = u * 512 + tid;
      int r = idx >> 3, sl = (idx & 7) ^ (r & 7);
      gload16(BT + (bcol0 + r) * (long)K + kof + sl * 8,
              bbase + (u * 512 + wv * 64) * 8);
    }
  };

  f32x4 acc[MI][NI] = {};
  STAGE(0);
  STAGE(1);
  for (int t = 0; t < NT; ++t){
    const int cur = t & 1;
    if (t + 1 < NT){
      if constexpr (CFG == 0) asm volatile("s_waitcnt vmcnt(8)" ::: "memory");
      else                    asm volatile("s_waitcnt vmcnt(6)" ::: "memory");
    } else {
      asm volatile("s_waitcnt vmcnt(0)" ::: "memory");
    }
    __builtin_amdgcn_s_barrier();            // all waves: buf[cur] fully staged
    __builtin_amdgcn_sched_barrier(0);
    const short* as = &As[cur][0];
    const short* bs = &Bs[cur][0];
    #pragma unroll
    for (int ks = 0; ks < 2; ++ks){
      s16x8 af[MI], bfv[NI];
      #pragma unroll
      for (int mi = 0; mi < MI; ++mi){
        int R = wr * (MI * 16) + mi * 16 + lr;
        int sg = ks * 4 + lg;
        af[mi] = *(const s16x8*)&as[R * 64 + ((sg ^ (R & 7)) << 3)];
      }
      #pragma unroll
      for (int ni = 0; ni < NI; ++ni){
        int R = wc * 64 + ni * 16 + lr;
        int sg = ks * 4 + lg;
        bfv[ni] = *(const s16x8*)&bs[R * 64 + ((sg ^ (R & 7)) << 3)];
      }
      __builtin_amdgcn_s_setprio(1);
      #pragma unroll
      for (int mi = 0; mi < MI; ++mi)
        #pragma unroll
        for (int ni = 0; ni < NI; ++ni)
          acc[mi][ni] = __builtin_amdgcn_mfma_f32_16x16x32_bf16(af[mi], bfv[ni], acc[mi][ni], 0, 0, 0);
      __builtin_amdgcn_s_setprio(0);
    }
    asm volatile("s_waitcnt lgkmcnt(0)" ::: "memory");
    __builtin_amdgcn_sched_barrier(0);
    __builtin_amdgcn_s_barrier();            // all waves done reading buf[cur]
    __builtin_amdgcn_sched_barrier(0);
    if (t + 2 < NT) STAGE(t + 2);            // overwrite freed buffer
  }

  const int rb = lg * 4;   // C/D: col = lane&15, row = (lane>>4)*4 + reg
  #pragma unroll
  for (int mi = 0; mi < MI; ++mi){
    #pragma unroll
    for (int ni = 0; ni < NI; ++ni){
      int cl = (int)bcol0 + wc * 64 + ni * 16 + lr;
      float bv = bias[cl];
      #pragma unroll
      for (int i = 0; i < 4; ++i){
        long rl = arow0 + wr * (MI * 16) + mi * 16 + rb + i;
        float v = acc[mi][ni][i] + bv;
        if constexpr (EPI == 0){
          Hout[rl * (long)N + cl] = f2bf(gelu_f(v));
        } else {
          float rr = bf2f(resid[(row0_abs + rl) * 1024 + cl]);
          Fout[(row0_abs + rl) * 1024 + cl] = v + rr;
        }
      }
    }
  }
}

// ---------------- LN2 in-place on f32 out ----------------
__global__ __launch_bounds__(256) void ln2_k(float* __restrict__ out,
    const float* __restrict__ g, const float* __restrict__ bb){
  size_t row = blockIdx.x;
  int tid = threadIdx.x;
  float* p = out + row * 1024;
  f32x4 v = *(const f32x4*)(p + tid * 4);
  float sum = v[0] + v[1] + v[2] + v[3];
  float sq  = v[0]*v[0] + v[1]*v[1] + v[2]*v[2] + v[3]*v[3];
  for (int off = 32; off; off >>= 1){ sum += __shfl_down(sum, off); sq += __shfl_down(sq, off); }
  __shared__ float rs[4], rq[4];
  int lane = tid & 63, w = tid >> 6;
  if (lane == 0){ rs[w] = sum; rq[w] = sq; }
  __syncthreads();
  sum = rs[0] + rs[1] + rs[2] + rs[3]; sq = rq[0] + rq[1] + rq[2] + rq[3];
  float mu = sum * (1.0f / 1024.0f);
  float var = sq * (1.0f / 1024.0f) - mu * mu;
  float sc = rsqrtf(var + 1e-5f);
  f32x4 o;
  #pragma unroll
  for (int j = 0; j < 4; ++j){
    int d = tid * 4 + j;
    o[j] = (v[j] - mu) * sc * g[d] + bb[d];
  }
  *(f32x4*)(p + tid * 4) = o;
}

// ---------------- launch ----------------
extern "C" void kernel_launch(void* const* d_in, const int* in_sizes, int n_in,
                              void* d_out, int out_size, void* d_ws, size_t ws_size,
                              hipStream_t stream){
  (void)in_sizes; (void)n_in; (void)out_size; (void)ws_size;
  const int*   tokens = (const int*)d_in[0];
  const float* frw  = (const float*)d_in[1];
  const float* fiw  = (const float*)d_in[2];
  const float* mw   = (const float*)d_in[3];
  const float* po   = (const float*)d_in[4];
  const float* ftew = (const float*)d_in[5];
  const float* fteb = (const float*)d_in[6];
  const float* posph= (const float*)d_in[7];
  const float* awr  = (const float*)d_in[8];
  const float* awi  = (const float*)d_in[9];
  const float* ln1g = (const float*)d_in[10];
  const float* ln1b = (const float*)d_in[11];
  const float* w1   = (const float*)d_in[12];
  const float* b1   = (const float*)d_in[13];
  const float* w2   = (const float*)d_in[14];
  const float* b2   = (const float*)d_in[15];
  const float* ln2g = (const float*)d_in[16];
  const float* ln2b = (const float*)d_in[17];
  float* out = (float*)d_out;

  char* ws = (char*)d_ws;
  size_t o = 0;
  float* residual = (float*)(ws + o); o += (size_t)16384 * 1024 * 4;  // 67.1 MB; later hbuf
  short* xln1     = (short*)(ws + o); o += (size_t)16384 * 1024 * 2;  // 33.6 MB
  short* w1b      = (short*)(ws + o); o += (size_t)4096 * 1024 * 2;   //  8.4 MB
  short* w2b      = (short*)(ws + o); o += (size_t)4096 * 1024 * 2;   //  8.4 MB
  float* ctab     = (float*)(ws + o); o += 524288;
  float* stab     = (float*)(ws + o); o += 524288;
  float* Xr       = (float*)(ws + o); o += 524288;
  float* Xi       = (float*)(ws + o); o += 524288;
  float* Or       = (float*)(ws + o); o += 524288;
  float* Oi       = (float*)(ws + o); o += 524288;
  float* Pr       = (float*)(ws + o); o += (size_t)8 * 4 * 1024 * 32 * 4;
  float* Pi       = (float*)(ws + o); o += (size_t)8 * 4 * 1024 * 32 * 4;
  float* wcs      = (float*)(ws + o); o += 512;
  short* hbuf     = (short*)residual;   // 8192x4096 bf16 aliases dead residual

  prep_wcs_k<<<1, 64, 0, stream>>>(mw, po, wcs);
  prep_tab_k<<<512, 256, 0, stream>>>(ctab, stab);
  transpose_bf16_k<<<dim3(64, 16), 256, 0, stream>>>(w1, w1b, 1024, 4096);
  transpose_bf16_k<<<dim3(16, 64), 256, 0, stream>>>(w2, w2b, 4096, 1024);

  kernelA<<<4096, 256, 0, stream>>>(tokens, frw, fiw, wcs, ftew, fteb, posph, residual);
  kernelB2<<<1024, 256, 0, stream>>>(residual, Pr, Pi);
  reduceB_k<<<512, 256, 0, stream>>>(Pr, Pi, Xr, Xi);
  kernelC<<<256, 128, 0, stream>>>(Xr, Xi, awr, awi, Or, Oi);
  kernelD1<<<512, 256, 0, stream>>>(Or, Oi, ctab, stab, residual);
  ln1_k<<<16384, 256, 0, stream>>>(residual, ln1g, ln1b, xln1);

  for (int c = 0; c < 2; ++c){
    long row0 = (long)c * 8192;
    gemm8_k<0, 0><<<dim3(32, 16), 512, 0, stream>>>(xln1 + row0 * 1024, w1b, b1,
                                                    nullptr, hbuf, nullptr, 1024, 4096, 0);
    gemm8_k<1, 1><<<dim3(32, 8), 512, 0, stream>>>(hbuf, w2b, b2,
                                                   xln1, nullptr, out, 4096, 1024, row0);
  }
  ln2_k<<<16384, 256, 0, stream>>>(out, ln2g, ln2b);
}

// Round 4
// 624.732 us; speedup vs baseline: 1.6313x; 1.0031x over previous
//
#include <hip/hip_runtime.h>

// WaveInputEncoder on MI355X — round 4.
// vs r3: GEMMs ported from 2-phase to the 8-phase-style per-quadrant interleave
// (T3+T4: counted vmcnt(6/8) twice per K-tile, never drained in-loop; one
// half-tile staged per phase; T2 swizzle; T5 setprio; T1 XCD swizzle).
// kernelD1 + ln1 fused into kernelD2 (irfft + residual + LN1 -> bf16).

typedef __attribute__((ext_vector_type(8))) short s16x8;
typedef __attribute__((ext_vector_type(4))) short s16x4;
typedef __attribute__((ext_vector_type(4))) float f32x4;

#define SCHED0 __builtin_amdgcn_sched_barrier(0)
#define BARR   __builtin_amdgcn_s_barrier()
#define LGKM0  asm volatile("s_waitcnt lgkmcnt(0)" ::: "memory")
#define VM(n)  asm volatile("s_waitcnt vmcnt(" #n ")" ::: "memory")

__device__ __forceinline__ short f2bf(float x){
  unsigned u = __float_as_uint(x);
  unsigned r = (u + 0x7fffu + ((u >> 16) & 1u)) >> 16;   // RNE
  return (short)r;
}
__device__ __forceinline__ float bf2f(short x){
  return __uint_as_float(((unsigned)(unsigned short)x) << 16);
}
__device__ __forceinline__ void gload16(const void* g, void* l){
  __builtin_amdgcn_global_load_lds((const __attribute__((address_space(1))) void*)g,
                                   (__attribute__((address_space(3))) void*)l, 16, 0, 0);
}
__device__ __forceinline__ float gelu_f(float v){
  float u2 = v * (0.7978845608f + 0.0356774081f * v * v);
  float e = __expf(2.0f * u2);
  float th = 1.0f - 2.0f / (e + 1.0f);
  return 0.5f * v * (1.0f + th);
}

// ---------------- prep kernels ----------------
__global__ void prep_wcs_k(const float* __restrict__ mw, const float* __restrict__ po,
                           float* __restrict__ wcs){
  int i = threadIdx.x;
  if (i < 32){
    wcs[i]      = log1pf(expf(mw[i]));  // softplus
    wcs[32 + i] = cosf(po[i]);
    wcs[64 + i] = sinf(po[i]);
  }
}

__global__ __launch_bounds__(256) void prep_tab_k(float* __restrict__ ctab, float* __restrict__ stab){
  int idx = blockIdx.x * 256 + threadIdx.x;      // idx = m*4096 + t
  int m = idx >> 12, t = idx & 4095;
  int r = (m * t) & 4095;
  float ang = (float)r * 1.5339807878856412e-3f; // 2*pi/4096
  float s, c; sincosf(ang, &s, &c);
  ctab[idx] = c; stab[idx] = s;
}

// transpose fp32 (R x C) -> bf16 (C x R), 64x64 LDS tiles
__global__ __launch_bounds__(256) void transpose_bf16_k(const float* __restrict__ src,
                                                        short* __restrict__ dst,
                                                        int R, int C){
  __shared__ float tile[64][65];
  int c0 = blockIdx.x * 64, r0 = blockIdx.y * 64;
  for (int i = 0; i < 16; ++i){
    int idx = i * 256 + threadIdx.x;
    int rr = idx >> 6, cc = idx & 63;
    tile[rr][cc] = src[(size_t)(r0 + rr) * C + c0 + cc];
  }
  __syncthreads();
  for (int i = 0; i < 16; ++i){
    int idx = i * 256 + threadIdx.x;
    int cc = idx >> 6, rr = idx & 63;
    dst[(size_t)(c0 + cc) * R + r0 + rr] = f2bf(tile[rr][cc]);
  }
}

// ---------------- kernel A ----------------
__global__ __launch_bounds__(256) void kernelA(const int* __restrict__ tokens,
    const float* __restrict__ frw, const float* __restrict__ fiw,
    const float* __restrict__ wcs, const float* __restrict__ ftew,
    const float* __restrict__ fteb, const float* __restrict__ posph,
    float* __restrict__ xout){
  __shared__ float ffs[4][64];
  __shared__ float xs[4][1024];
  __shared__ float wsh[96];
  int tid = threadIdx.x;
  int b = blockIdx.x >> 10, t0 = (blockIdx.x & 1023) * 4;
  if (tid < 96) wsh[tid] = wcs[tid];
  __syncthreads();
  if (tid < 128){
    int tk = tid >> 5, m = tid & 31;
    int tok = tokens[b * 4096 + t0 + tk];
    float w = wsh[m];
    float re = frw[(size_t)tok * 32 + m] * w;
    float im = fiw[(size_t)tok * 32 + m] * w;
    float c = wsh[32 + m], s = wsh[64 + m];
    ffs[tk][m]      = re * c - im * s;
    ffs[tk][32 + m] = re * s + im * c;
  }
  __syncthreads();
  for (int p = 0; p < 4; ++p){
    int dd = p * 256 + tid;
    float bb = fteb[dd];
    float a0 = bb, a1 = bb, a2 = bb, a3 = bb;
    #pragma unroll 8
    for (int k = 0; k < 64; ++k){
      float wv = ftew[k * 1024 + dd];
      a0 += ffs[0][k] * wv; a1 += ffs[1][k] * wv;
      a2 += ffs[2][k] * wv; a3 += ffs[3][k] * wv;
    }
    xs[0][dd] = a0; xs[1][dd] = a1; xs[2][dd] = a2; xs[3][dd] = a3;
  }
  __syncthreads();
  for (int p = 0; p < 4; ++p){
    int dd = p * 256 + tid, dm = (dd + 1023) & 1023;
    #pragma unroll
    for (int tk = 0; tk < 4; ++tk){
      float pp = posph[(size_t)(t0 + tk) * 1024 + dd];
      float p2 = pp * pp;
      float sp = pp * (1.0f - p2 * (1.0f/6.0f) + p2 * p2 * (1.0f/120.0f));
      float cp = 1.0f - p2 * 0.5f + p2 * p2 * (1.0f/24.0f);
      xout[((size_t)b * 4096 + t0 + tk) * 1024 + dd] = xs[tk][dd] * cp + xs[tk][dm] * sp;
    }
  }
}

// ---------------- kernel B: truncated forward DFT via rotation recurrence ----------------
__global__ __launch_bounds__(256) void kernelB2(const float* __restrict__ xin,
    float* __restrict__ Pr, float* __restrict__ Pi){
  __shared__ float xsh[64][32];
  int tid = threadIdx.x;
  int bx = blockIdx.x;
  int b = bx >> 8, dch = (bx >> 3) & 31, tc = bx & 7;
  int d0 = dch * 32;
  int t_start = tc * 512;
  int dg = tid >> 5, m = tid & 31;
  const float TPN = 1.5339807878856412e-3f;
  int r0 = (m * t_start) & 4095;
  float cw, sw; sincosf(-(float)r0 * TPN, &sw, &cw);
  float cs, ss; sincosf(-(float)m * TPN, &ss, &cs);
  float ar[4] = {0,0,0,0}, ai[4] = {0,0,0,0};
  for (int t0 = t_start; t0 < t_start + 512; t0 += 64){
    __syncthreads();
    #pragma unroll
    for (int i = 0; i < 2; ++i){
      int unit = i * 256 + tid;
      int tt = unit >> 3, du = (unit & 7) * 4;
      *(f32x4*)&xsh[tt][du] = *(const f32x4*)&xin[((size_t)b * 4096 + t0 + tt) * 1024 + d0 + du];
    }
    __syncthreads();
    #pragma unroll 4
    for (int tt = 0; tt < 64; ++tt){
      f32x4 xv = *(const f32x4*)&xsh[tt][dg * 4];
      #pragma unroll
      for (int j = 0; j < 4; ++j){ ar[j] += xv[j] * cw; ai[j] += xv[j] * sw; }
      float cn = cw * cs - sw * ss;
      sw = cw * ss + sw * cs; cw = cn;
    }
  }
  #pragma unroll
  for (int j = 0; j < 4; ++j){
    int d = d0 + dg * 4 + j;
    size_t idx = (((size_t)tc * 4 + b) * 1024 + d) * 32 + m;
    Pr[idx] = ar[j]; Pi[idx] = ai[j];
  }
}

__global__ __launch_bounds__(256) void reduceB_k(const float* __restrict__ Pr,
    const float* __restrict__ Pi, float* __restrict__ Xr, float* __restrict__ Xi){
  int lin = blockIdx.x * 256 + threadIdx.x;
  int m = lin & 31, d = (lin >> 5) & 1023, b = lin >> 15;
  float sr = 0.0f, si = 0.0f;
  for (int tc = 0; tc < 8; ++tc){
    size_t idx = (((size_t)tc * 4 + b) * 1024 + d) * 32 + m;
    sr += Pr[idx]; si += Pi[idx];
  }
  int n = d >> 7, jj = d & 127;
  size_t o = (((size_t)b * 8 + n) * 32 + m) * 128 + jj;
  Xr[o] = sr * 0.015625f; Xi[o] = si * 0.015625f;
}

// ---------------- kernel C ----------------
__global__ __launch_bounds__(128) void kernelC(const float* __restrict__ Xr, const float* __restrict__ Xi,
    const float* __restrict__ awr, const float* __restrict__ awi,
    float* __restrict__ Or, float* __restrict__ Oi){
  __shared__ float xr_s[4][128], xi_s[4][128];
  int nm = blockIdx.x; int n = nm >> 5, m = nm & 31;
  int i = threadIdx.x;
  for (int b = 0; b < 4; ++b){
    size_t src = (((size_t)b * 8 + n) * 32 + m) * 128 + i;
    xr_s[b][i] = Xr[src]; xi_s[b][i] = Xi[src];
  }
  __syncthreads();
  float accr[4] = {0,0,0,0}, acci[4] = {0,0,0,0};
  size_t wb = (((size_t)n * 32 + m) * 128 + i) * 128;
  for (int j = 0; j < 128; ++j){
    float wr = awr[wb + j], wi = awi[wb + j];
    #pragma unroll
    for (int b = 0; b < 4; ++b){
      accr[b] += wr * xr_s[b][j] - wi * xi_s[b][j];
      acci[b] += wr * xi_s[b][j] + wi * xr_s[b][j];
    }
  }
  #pragma unroll
  for (int b = 0; b < 4; ++b){
    float vr = accr[b], vi = acci[b];
    vr = vr > 0.01f ? vr - 0.01f : (vr < -0.01f ? vr + 0.01f : 0.0f);
    vi = vi > 0.01f ? vi - 0.01f : (vi < -0.01f ? vi + 0.01f : 0.0f);
    size_t dst = ((size_t)b * 32 + m) * 1024 + n * 128 + i;  // [b][m][d]
    Or[dst] = vr; Oi[dst] = vi;
  }
}

// ---------------- kernel D2: tiled irfft + residual + LN1 -> bf16 (fused) ----------------
// grid 512 = b(4) x tgroup(128, 32 t each); block 256 = t2(16) x dl(16)
__global__ __launch_bounds__(256) void kernelD2(const float* __restrict__ Or, const float* __restrict__ Oi,
    const float* __restrict__ ctab, const float* __restrict__ stab,
    const float* __restrict__ residual, const float* __restrict__ g1,
    const float* __restrict__ b1v, short* __restrict__ xln1){
  __shared__ float cts[32][32], sts[32][32];
  __shared__ float Ors[32][256], Ois[32][256];
  int tid = threadIdx.x;
  int b = blockIdx.x >> 7, t0 = (blockIdx.x & 127) * 32;
  for (int i = 0; i < 4; ++i){
    int lin = i * 256 + tid;
    int m = lin >> 5, tt = lin & 31;
    float f = (m == 0 ? 1.0f : 2.0f) * 0.015625f;
    cts[m][tt] = ctab[m * 4096 + t0 + tt] * f;
    sts[m][tt] = stab[m * 4096 + t0 + tt] * f;
  }
  int t2 = tid >> 4, dl = tid & 15;
  int r0 = t0 + t2 * 2;
  float vals[4][2][16];
  float sum0 = 0.f, sum1 = 0.f, sq0 = 0.f, sq1 = 0.f;
  #pragma unroll
  for (int c = 0; c < 4; ++c){
    __syncthreads();
    for (int i = 0; i < 8; ++i){
      int lin = i * 256 + tid;           // 2048 quads = 32m x 64dq
      int m = lin >> 6, dq = lin & 63;
      int loc = dq * 4;
      int ph = loc ^ ((loc >> 3) & 0x1C);   // bank-spread involution
      size_t src = ((size_t)b * 32 + m) * 1024 + c * 256 + loc;
      *(f32x4*)&Ors[m][ph] = *(const f32x4*)&Or[src];
      *(f32x4*)&Ois[m][ph] = *(const f32x4*)&Oi[src];
    }
    __syncthreads();
    float a0[16], a1[16];
    #pragma unroll
    for (int j = 0; j < 16; ++j){ a0[j] = 0.f; a1[j] = 0.f; }
    for (int m = 0; m < 32; ++m){
      float c0 = cts[m][t2 * 2],     s0 = sts[m][t2 * 2];
      float c1 = cts[m][t2 * 2 + 1], s1 = sts[m][t2 * 2 + 1];
      #pragma unroll
      for (int jj = 0; jj < 4; ++jj){
        int loc = dl * 16 + jj * 4;
        int ph = loc ^ ((loc >> 3) & 0x1C);
        f32x4 orv = *(const f32x4*)&Ors[m][ph];
        f32x4 oiv = *(const f32x4*)&Ois[m][ph];
        #pragma unroll
        for (int e = 0; e < 4; ++e){
          a0[jj*4+e] += c0 * orv[e] - s0 * oiv[e];
          a1[jj*4+e] += c1 * orv[e] - s1 * oiv[e];
        }
      }
    }
    size_t rb0 = ((size_t)b * 4096 + r0) * 1024 + c * 256 + dl * 16;
    #pragma unroll
    for (int jj = 0; jj < 4; ++jj){
      f32x4 rv0 = *(const f32x4*)&residual[rb0 + jj * 4];
      f32x4 rv1 = *(const f32x4*)&residual[rb0 + 1024 + jj * 4];
      #pragma unroll
      for (int e = 0; e < 4; ++e){
        float v0 = a0[jj*4+e] + rv0[e];
        float v1 = a1[jj*4+e] + rv1[e];
        vals[c][0][jj*4+e] = v0; sum0 += v0; sq0 += v0 * v0;
        vals[c][1][jj*4+e] = v1; sum1 += v1; sq1 += v1 * v1;
      }
    }
  }
  #pragma unroll
  for (int off = 1; off < 16; off <<= 1){
    sum0 += __shfl_xor(sum0, off); sq0 += __shfl_xor(sq0, off);
    sum1 += __shfl_xor(sum1, off); sq1 += __shfl_xor(sq1, off);
  }
  float mu0 = sum0 * (1.0f/1024.0f), mu1 = sum1 * (1.0f/1024.0f);
  float sc0 = rsqrtf(sq0 * (1.0f/1024.0f) - mu0 * mu0 + 1e-5f);
  float sc1 = rsqrtf(sq1 * (1.0f/1024.0f) - mu1 * mu1 + 1e-5f);
  #pragma unroll
  for (int c = 0; c < 4; ++c){
    int dbase = c * 256 + dl * 16;
    #pragma unroll
    for (int h = 0; h < 2; ++h){
      s16x8 o0, o1;
      #pragma unroll
      for (int e = 0; e < 8; ++e){
        int j = h * 8 + e;
        float gv = g1[dbase + j], bv = b1v[dbase + j];
        o0[e] = f2bf((vals[c][0][j] - mu0) * sc0 * gv + bv);
        o1[e] = f2bf((vals[c][1][j] - mu1) * sc1 * gv + bv);
      }
      size_t ob = ((size_t)b * 4096 + r0) * 1024 + dbase + h * 8;
      *(s16x8*)&xln1[ob] = o0;
      *(s16x8*)&xln1[ob + 1024] = o1;
    }
  }
}

// ---------------- per-quadrant-phase pipelined bf16 MFMA GEMM ----------------
// BM=256, BK=64, 8 waves (2M x 4N). CFG0: BN=256 (NI=4); CFG1: BN=128 (NI=2).
// Row-interleaved fragment map: A row = mi*32 + wr*16 + lr (half h = rows h*128..).
// Per K-tile: 4 phases (CFG0) / 2 phases (CFG1); one stage-half per phase;
// counted vmcnt (steady 6 or 8), drained only at the last tile.
template<int CFG, int EPI>
__global__ __launch_bounds__(512, 2) void gemm8p_k(const short* __restrict__ A,
    const short* __restrict__ BT, const float* __restrict__ bias,
    const short* __restrict__ resid, short* __restrict__ Hout,
    float* __restrict__ Fout, int K, int N, long row0_abs, int nMB){
  constexpr int BN = (CFG == 0) ? 256 : 128;
  constexpr int NI = (CFG == 0) ? 4 : 2;
  __shared__ __align__(16) short As[2][256 * 64];
  __shared__ __align__(16) short Bs[2][BN * 64];
  const int tid = threadIdx.x;
  const int lane = tid & 63, wv = tid >> 6;
  const int wr = wv >> 2, wc = wv & 3;
  const int lr = lane & 15, lg = lane >> 4;
  const int wrlr = wr * 16 + lr;

  // XCD-aware bijective swizzle (nwg % 8 == 0 for both grids)
  int nwg = gridDim.x;
  int flat = blockIdx.x;
  int swz = (flat & 7) * (nwg >> 3) + (flat >> 3);
  int mb = swz % nMB, nb = swz / nMB;
  const long arow0 = (long)mb * 256;
  const long bcol0 = (long)nb * BN;
  const int NT = K >> 6;

  auto stageA = [&](int t, int h){
    short* dst = &As[t & 1][h * 128 * 64];
    const short* src = A + (arow0 + h * 128) * (long)K + (long)t * 64;
    #pragma unroll
    for (int u = 0; u < 2; ++u){
      int idx = u * 512 + tid;
      int r = idx >> 3, sl = (idx & 7) ^ (r & 7);
      gload16(src + (long)r * K + sl * 8, dst + (u * 512 + wv * 64) * 8);
    }
  };
  auto stageB = [&](int t, int h){
    short* dst = &Bs[t & 1][h * 128 * 64];
    const short* src = BT + (bcol0 + h * 128) * (long)K + (long)t * 64;
    #pragma unroll
    for (int u = 0; u < 2; ++u){
      int idx = u * 512 + tid;
      int r = idx >> 3, sl = (idx & 7) ^ (r & 7);
      gload16(src + (long)r * K + sl * 8, dst + (u * 512 + wv * 64) * 8);
    }
  };

  f32x4 acc[8][NI] = {};
  s16x8 af[4][2], bfl[2][2], bfh[2][2];

  auto loadA4 = [&](const short* as, int mib){
    #pragma unroll
    for (int mi = 0; mi < 4; ++mi)
      #pragma unroll
      for (int ks = 0; ks < 2; ++ks){
        int R = (mib + mi) * 32 + wrlr;
        af[mi][ks] = *(const s16x8*)&as[R * 64 + (((ks * 4 + lg) ^ (R & 7)) << 3)];
      }
  };
  auto loadB2 = [&](const short* bs, s16x8 (&bf)[2][2], int nib){
    #pragma unroll
    for (int ni = 0; ni < 2; ++ni)
      #pragma unroll
      for (int ks = 0; ks < 2; ++ks){
        int R = (CFG == 0) ? ((nib + ni) * 64 + wc * 16 + lr)
                           : (wc * 32 + (nib + ni) * 16 + lr);
        bf[ni][ks] = *(const s16x8*)&bs[R * 64 + (((ks * 4 + lg) ^ (R & 7)) << 3)];
      }
  };
  auto mfmaQ = [&](s16x8 (&bf)[2][2], int mib, int nib){
    __builtin_amdgcn_s_setprio(1);
    #pragma unroll
    for (int ks = 0; ks < 2; ++ks)
      #pragma unroll
      for (int mi = 0; mi < 4; ++mi)
        #pragma unroll
        for (int ni = 0; ni < 2; ++ni)
          acc[mib + mi][nib + ni] = __builtin_amdgcn_mfma_f32_16x16x32_bf16(
              af[mi][ks], bf[ni][ks], acc[mib + mi][nib + ni], 0, 0, 0);
    __builtin_amdgcn_s_setprio(0);
  };

  if constexpr (CFG == 0){
    // prologue stream: A0(0), B1(0), B0(0), A1(0), A0(1), B1(1)
    stageA(0,0); stageB(0,1); stageB(0,0); stageA(0,1); stageA(1,0); stageB(1,1);
    VM(6); SCHED0; BARR; SCHED0;
    for (int t = 0; t < NT; ++t){
      const short* as = As[t & 1];
      const short* bs = Bs[t & 1];
      const bool s1 = (t + 1 < NT), s2 = (t + 2 < NT);
      // q0: read af_lo + bf_lo; stage B0(t+1); MFMA [0-3][0-1]
      loadA4(as, 0); loadB2(bs, bfl, 0);
      SCHED0; if (s1) stageB(t + 1, 0); SCHED0;
      BARR;
      mfmaQ(bfl, 0, 0);
      SCHED0; LGKM0; SCHED0; BARR; SCHED0;
      // q1: read bf_hi; stage A1(t+1); MFMA [0-3][2-3]; wait vmcnt(8)
      loadB2(bs, bfh, 2);
      SCHED0; if (s1) stageA(t + 1, 1); SCHED0;
      BARR;
      mfmaQ(bfh, 0, 2);
      SCHED0; LGKM0;
      if (s1) { VM(8); } else { VM(0); }
      SCHED0; BARR; SCHED0;
      // q2: read af_hi; stage A0(t+2); MFMA [4-7][0-1]
      loadA4(as, 4);
      SCHED0; if (s2) stageA(t + 2, 0); SCHED0;
      BARR;
      mfmaQ(bfl, 4, 0);
      SCHED0; LGKM0; SCHED0; BARR; SCHED0;
      // q3: stage B1(t+2); MFMA [4-7][2-3]; wait vmcnt(6)
      SCHED0; if (s2) stageB(t + 2, 1); SCHED0;
      BARR;
      mfmaQ(bfh, 4, 2);
      SCHED0;
      if (s1) { if (s2) { VM(6); } else { VM(2); } }
      SCHED0; BARR; SCHED0;
    }
  } else {
    // prologue stream: A0(0), B(0), A1(0), A0(1), B(1)
    stageA(0,0); stageB(0,0); stageA(0,1); stageA(1,0); stageB(1,0);
    VM(6); SCHED0; BARR; SCHED0;
    for (int t = 0; t < NT; ++t){
      const short* as = As[t & 1];
      const short* bs = Bs[t & 1];
      const bool s1 = (t + 1 < NT), s2 = (t + 2 < NT);
      // p0: read af_lo + bf; stage A1(t+1); MFMA [0-3][0-1]; wait vmcnt(6)
      loadA4(as, 0); loadB2(bs, bfl, 0);
      SCHED0; if (s1) stageA(t + 1, 1); SCHED0;
      BARR;
      mfmaQ(bfl, 0, 0);
      SCHED0; LGKM0;
      if (s1) { VM(6); } else { VM(0); }
      SCHED0; BARR; SCHED0;
      // p1: read af_hi; stage A0(t+2)+B(t+2); MFMA [4-7][0-1]; wait vmcnt(6)
      loadA4(as, 4);
      SCHED0; if (s2) { stageA(t + 2, 0); stageB(t + 2, 0); } SCHED0;
      BARR;
      mfmaQ(bfl, 4, 0);
      SCHED0; LGKM0;
      if (s1) { if (s2) { VM(6); } else { VM(2); } }
      SCHED0; BARR; SCHED0;
    }
  }

  SCHED0;
  // epilogue: C/D layout col = lane&15, row = (lane>>4)*4 + reg
  const int rb = lg * 4;
  #pragma unroll
  for (int mi = 0; mi < 8; ++mi){
    #pragma unroll
    for (int ni = 0; ni < NI; ++ni){
      int cl = (int)bcol0 + ((CFG == 0) ? (ni * 64 + wc * 16 + lr)
                                        : (wc * 32 + ni * 16 + lr));
      float bv = bias[cl];
      #pragma unroll
      for (int i = 0; i < 4; ++i){
        long rl = arow0 + mi * 32 + wr * 16 + rb + i;
        float v = acc[mi][ni][i] + bv;
        if constexpr (EPI == 0){
          Hout[rl * (long)N + cl] = f2bf(gelu_f(v));
        } else {
          float rr = bf2f(resid[(row0_abs + rl) * 1024 + cl]);
          Fout[(row0_abs + rl) * 1024 + cl] = v + rr;
        }
      }
    }
  }
}

// ---------------- LN2 in-place on f32 out ----------------
__global__ __launch_bounds__(256) void ln2_k(float* __restrict__ out,
    const float* __restrict__ g, const float* __restrict__ bb){
  size_t row = blockIdx.x;
  int tid = threadIdx.x;
  float* p = out + row * 1024;
  f32x4 v = *(const f32x4*)(p + tid * 4);
  float sum = v[0] + v[1] + v[2] + v[3];
  float sq  = v[0]*v[0] + v[1]*v[1] + v[2]*v[2] + v[3]*v[3];
  for (int off = 32; off; off >>= 1){ sum += __shfl_down(sum, off); sq += __shfl_down(sq, off); }
  __shared__ float rs[4], rq[4];
  int lane = tid & 63, w = tid >> 6;
  if (lane == 0){ rs[w] = sum; rq[w] = sq; }
  __syncthreads();
  sum = rs[0] + rs[1] + rs[2] + rs[3]; sq = rq[0] + rq[1] + rq[2] + rq[3];
  float mu = sum * (1.0f / 1024.0f);
  float var = sq * (1.0f / 1024.0f) - mu * mu;
  float sc = rsqrtf(var + 1e-5f);
  f32x4 o;
  #pragma unroll
  for (int j = 0; j < 4; ++j){
    int d = tid * 4 + j;
    o[j] = (v[j] - mu) * sc * g[d] + bb[d];
  }
  *(f32x4*)(p + tid * 4) = o;
}

// ---------------- launch ----------------
extern "C" void kernel_launch(void* const* d_in, const int* in_sizes, int n_in,
                              void* d_out, int out_size, void* d_ws, size_t ws_size,
                              hipStream_t stream){
  (void)in_sizes; (void)n_in; (void)out_size; (void)ws_size;
  const int*   tokens = (const int*)d_in[0];
  const float* frw  = (const float*)d_in[1];
  const float* fiw  = (const float*)d_in[2];
  const float* mw   = (const float*)d_in[3];
  const float* po   = (const float*)d_in[4];
  const float* ftew = (const float*)d_in[5];
  const float* fteb = (const float*)d_in[6];
  const float* posph= (const float*)d_in[7];
  const float* awr  = (const float*)d_in[8];
  const float* awi  = (const float*)d_in[9];
  const float* ln1g = (const float*)d_in[10];
  const float* ln1b = (const float*)d_in[11];
  const float* w1   = (const float*)d_in[12];
  const float* b1   = (const float*)d_in[13];
  const float* w2   = (const float*)d_in[14];
  const float* b2   = (const float*)d_in[15];
  const float* ln2g = (const float*)d_in[16];
  const float* ln2b = (const float*)d_in[17];
  float* out = (float*)d_out;

  char* ws = (char*)d_ws;
  size_t o = 0;
  float* residual = (float*)(ws + o); o += (size_t)16384 * 1024 * 4;  // 67.1 MB; later hbuf
  short* xln1     = (short*)(ws + o); o += (size_t)16384 * 1024 * 2;  // 33.6 MB
  short* w1b      = (short*)(ws + o); o += (size_t)4096 * 1024 * 2;
  short* w2b      = (short*)(ws + o); o += (size_t)4096 * 1024 * 2;
  float* ctab     = (float*)(ws + o); o += 524288;
  float* stab     = (float*)(ws + o); o += 524288;
  float* Xr       = (float*)(ws + o); o += 524288;
  float* Xi       = (float*)(ws + o); o += 524288;
  float* Or       = (float*)(ws + o); o += 524288;
  float* Oi       = (float*)(ws + o); o += 524288;
  float* Pr       = (float*)(ws + o); o += (size_t)8 * 4 * 1024 * 32 * 4;
  float* Pi       = (float*)(ws + o); o += (size_t)8 * 4 * 1024 * 32 * 4;
  float* wcs      = (float*)(ws + o); o += 512;
  short* hbuf     = (short*)residual;   // 8192x4096 bf16 aliases dead residual

  prep_wcs_k<<<1, 64, 0, stream>>>(mw, po, wcs);
  prep_tab_k<<<512, 256, 0, stream>>>(ctab, stab);
  transpose_bf16_k<<<dim3(64, 16), 256, 0, stream>>>(w1, w1b, 1024, 4096);
  transpose_bf16_k<<<dim3(16, 64), 256, 0, stream>>>(w2, w2b, 4096, 1024);

  kernelA<<<4096, 256, 0, stream>>>(tokens, frw, fiw, wcs, ftew, fteb, posph, residual);
  kernelB2<<<1024, 256, 0, stream>>>(residual, Pr, Pi);
  reduceB_k<<<512, 256, 0, stream>>>(Pr, Pi, Xr, Xi);
  kernelC<<<256, 128, 0, stream>>>(Xr, Xi, awr, awi, Or, Oi);
  kernelD2<<<512, 256, 0, stream>>>(Or, Oi, ctab, stab, residual, ln1g, ln1b, xln1);

  for (int c = 0; c < 2; ++c){
    long row0 = (long)c * 8192;
    gemm8p_k<0, 0><<<512, 512, 0, stream>>>(xln1 + row0 * 1024, w1b, b1,
                                            nullptr, hbuf, nullptr, 1024, 4096, 0, 32);
    gemm8p_k<1, 1><<<256, 512, 0, stream>>>(hbuf, w2b, b2,
                                            xln1, nullptr, out, 4096, 1024, row0, 32);
  }
  ln2_k<<<16384, 256, 0, stream>>>(out, ln2g, ln2b);
}

// Round 5
// 586.367 us; speedup vs baseline: 1.7380x; 1.0654x over previous
//
#include <hip/hip_runtime.h>

// WaveInputEncoder on MI355X — round 5.
// vs r4: kernelD2 (fused, occupancy-starved, 109us) replaced by kernelD3
// (d-chunked irfft + residual in-place, 2048 blocks, conflict-free LDS stagger)
// + ln1_k (r2 version). GEMMs and everything else unchanged.

typedef __attribute__((ext_vector_type(8))) short s16x8;
typedef __attribute__((ext_vector_type(4))) short s16x4;
typedef __attribute__((ext_vector_type(4))) float f32x4;

#define SCHED0 __builtin_amdgcn_sched_barrier(0)
#define BARR   __builtin_amdgcn_s_barrier()
#define LGKM0  asm volatile("s_waitcnt lgkmcnt(0)" ::: "memory")
#define VM(n)  asm volatile("s_waitcnt vmcnt(" #n ")" ::: "memory")

__device__ __forceinline__ short f2bf(float x){
  unsigned u = __float_as_uint(x);
  unsigned r = (u + 0x7fffu + ((u >> 16) & 1u)) >> 16;   // RNE
  return (short)r;
}
__device__ __forceinline__ float bf2f(short x){
  return __uint_as_float(((unsigned)(unsigned short)x) << 16);
}
__device__ __forceinline__ void gload16(const void* g, void* l){
  __builtin_amdgcn_global_load_lds((const __attribute__((address_space(1))) void*)g,
                                   (__attribute__((address_space(3))) void*)l, 16, 0, 0);
}
__device__ __forceinline__ float gelu_f(float v){
  float u2 = v * (0.7978845608f + 0.0356774081f * v * v);
  float e = __expf(2.0f * u2);
  float th = 1.0f - 2.0f / (e + 1.0f);
  return 0.5f * v * (1.0f + th);
}

// ---------------- prep kernels ----------------
__global__ void prep_wcs_k(const float* __restrict__ mw, const float* __restrict__ po,
                           float* __restrict__ wcs){
  int i = threadIdx.x;
  if (i < 32){
    wcs[i]      = log1pf(expf(mw[i]));  // softplus
    wcs[32 + i] = cosf(po[i]);
    wcs[64 + i] = sinf(po[i]);
  }
}

__global__ __launch_bounds__(256) void prep_tab_k(float* __restrict__ ctab, float* __restrict__ stab){
  int idx = blockIdx.x * 256 + threadIdx.x;      // idx = m*4096 + t
  int m = idx >> 12, t = idx & 4095;
  int r = (m * t) & 4095;
  float ang = (float)r * 1.5339807878856412e-3f; // 2*pi/4096
  float s, c; sincosf(ang, &s, &c);
  ctab[idx] = c; stab[idx] = s;
}

// transpose fp32 (R x C) -> bf16 (C x R), 64x64 LDS tiles
__global__ __launch_bounds__(256) void transpose_bf16_k(const float* __restrict__ src,
                                                        short* __restrict__ dst,
                                                        int R, int C){
  __shared__ float tile[64][65];
  int c0 = blockIdx.x * 64, r0 = blockIdx.y * 64;
  for (int i = 0; i < 16; ++i){
    int idx = i * 256 + threadIdx.x;
    int rr = idx >> 6, cc = idx & 63;
    tile[rr][cc] = src[(size_t)(r0 + rr) * C + c0 + cc];
  }
  __syncthreads();
  for (int i = 0; i < 16; ++i){
    int idx = i * 256 + threadIdx.x;
    int cc = idx >> 6, rr = idx & 63;
    dst[(size_t)(c0 + cc) * R + r0 + rr] = f2bf(tile[rr][cc]);
  }
}

// ---------------- kernel A ----------------
__global__ __launch_bounds__(256) void kernelA(const int* __restrict__ tokens,
    const float* __restrict__ frw, const float* __restrict__ fiw,
    const float* __restrict__ wcs, const float* __restrict__ ftew,
    const float* __restrict__ fteb, const float* __restrict__ posph,
    float* __restrict__ xout){
  __shared__ float ffs[4][64];
  __shared__ float xs[4][1024];
  __shared__ float wsh[96];
  int tid = threadIdx.x;
  int b = blockIdx.x >> 10, t0 = (blockIdx.x & 1023) * 4;
  if (tid < 96) wsh[tid] = wcs[tid];
  __syncthreads();
  if (tid < 128){
    int tk = tid >> 5, m = tid & 31;
    int tok = tokens[b * 4096 + t0 + tk];
    float w = wsh[m];
    float re = frw[(size_t)tok * 32 + m] * w;
    float im = fiw[(size_t)tok * 32 + m] * w;
    float c = wsh[32 + m], s = wsh[64 + m];
    ffs[tk][m]      = re * c - im * s;
    ffs[tk][32 + m] = re * s + im * c;
  }
  __syncthreads();
  for (int p = 0; p < 4; ++p){
    int dd = p * 256 + tid;
    float bb = fteb[dd];
    float a0 = bb, a1 = bb, a2 = bb, a3 = bb;
    #pragma unroll 8
    for (int k = 0; k < 64; ++k){
      float wv = ftew[k * 1024 + dd];
      a0 += ffs[0][k] * wv; a1 += ffs[1][k] * wv;
      a2 += ffs[2][k] * wv; a3 += ffs[3][k] * wv;
    }
    xs[0][dd] = a0; xs[1][dd] = a1; xs[2][dd] = a2; xs[3][dd] = a3;
  }
  __syncthreads();
  for (int p = 0; p < 4; ++p){
    int dd = p * 256 + tid, dm = (dd + 1023) & 1023;
    #pragma unroll
    for (int tk = 0; tk < 4; ++tk){
      float pp = posph[(size_t)(t0 + tk) * 1024 + dd];
      float p2 = pp * pp;
      float sp = pp * (1.0f - p2 * (1.0f/6.0f) + p2 * p2 * (1.0f/120.0f));
      float cp = 1.0f - p2 * 0.5f + p2 * p2 * (1.0f/24.0f);
      xout[((size_t)b * 4096 + t0 + tk) * 1024 + dd] = xs[tk][dd] * cp + xs[tk][dm] * sp;
    }
  }
}

// ---------------- kernel B: truncated forward DFT via rotation recurrence ----------------
__global__ __launch_bounds__(256) void kernelB2(const float* __restrict__ xin,
    float* __restrict__ Pr, float* __restrict__ Pi){
  __shared__ float xsh[64][32];
  int tid = threadIdx.x;
  int bx = blockIdx.x;
  int b = bx >> 8, dch = (bx >> 3) & 31, tc = bx & 7;
  int d0 = dch * 32;
  int t_start = tc * 512;
  int dg = tid >> 5, m = tid & 31;
  const float TPN = 1.5339807878856412e-3f;
  int r0 = (m * t_start) & 4095;
  float cw, sw; sincosf(-(float)r0 * TPN, &sw, &cw);
  float cs, ss; sincosf(-(float)m * TPN, &ss, &cs);
  float ar[4] = {0,0,0,0}, ai[4] = {0,0,0,0};
  for (int t0 = t_start; t0 < t_start + 512; t0 += 64){
    __syncthreads();
    #pragma unroll
    for (int i = 0; i < 2; ++i){
      int unit = i * 256 + tid;
      int tt = unit >> 3, du = (unit & 7) * 4;
      *(f32x4*)&xsh[tt][du] = *(const f32x4*)&xin[((size_t)b * 4096 + t0 + tt) * 1024 + d0 + du];
    }
    __syncthreads();
    #pragma unroll 4
    for (int tt = 0; tt < 64; ++tt){
      f32x4 xv = *(const f32x4*)&xsh[tt][dg * 4];
      #pragma unroll
      for (int j = 0; j < 4; ++j){ ar[j] += xv[j] * cw; ai[j] += xv[j] * sw; }
      float cn = cw * cs - sw * ss;
      sw = cw * ss + sw * cs; cw = cn;
    }
  }
  #pragma unroll
  for (int j = 0; j < 4; ++j){
    int d = d0 + dg * 4 + j;
    size_t idx = (((size_t)tc * 4 + b) * 1024 + d) * 32 + m;
    Pr[idx] = ar[j]; Pi[idx] = ai[j];
  }
}

__global__ __launch_bounds__(256) void reduceB_k(const float* __restrict__ Pr,
    const float* __restrict__ Pi, float* __restrict__ Xr, float* __restrict__ Xi){
  int lin = blockIdx.x * 256 + threadIdx.x;
  int m = lin & 31, d = (lin >> 5) & 1023, b = lin >> 15;
  float sr = 0.0f, si = 0.0f;
  for (int tc = 0; tc < 8; ++tc){
    size_t idx = (((size_t)tc * 4 + b) * 1024 + d) * 32 + m;
    sr += Pr[idx]; si += Pi[idx];
  }
  int n = d >> 7, jj = d & 127;
  size_t o = (((size_t)b * 8 + n) * 32 + m) * 128 + jj;
  Xr[o] = sr * 0.015625f; Xi[o] = si * 0.015625f;
}

// ---------------- kernel C ----------------
__global__ __launch_bounds__(128) void kernelC(const float* __restrict__ Xr, const float* __restrict__ Xi,
    const float* __restrict__ awr, const float* __restrict__ awi,
    float* __restrict__ Or, float* __restrict__ Oi){
  __shared__ float xr_s[4][128], xi_s[4][128];
  int nm = blockIdx.x; int n = nm >> 5, m = nm & 31;
  int i = threadIdx.x;
  for (int b = 0; b < 4; ++b){
    size_t src = (((size_t)b * 8 + n) * 32 + m) * 128 + i;
    xr_s[b][i] = Xr[src]; xi_s[b][i] = Xi[src];
  }
  __syncthreads();
  float accr[4] = {0,0,0,0}, acci[4] = {0,0,0,0};
  size_t wb = (((size_t)n * 32 + m) * 128 + i) * 128;
  for (int j = 0; j < 128; ++j){
    float wr = awr[wb + j], wi = awi[wb + j];
    #pragma unroll
    for (int b = 0; b < 4; ++b){
      accr[b] += wr * xr_s[b][j] - wi * xi_s[b][j];
      acci[b] += wr * xi_s[b][j] + wi * xr_s[b][j];
    }
  }
  #pragma unroll
  for (int b = 0; b < 4; ++b){
    float vr = accr[b], vi = acci[b];
    vr = vr > 0.01f ? vr - 0.01f : (vr < -0.01f ? vr + 0.01f : 0.0f);
    vi = vi > 0.01f ? vi - 0.01f : (vi < -0.01f ? vi + 0.01f : 0.0f);
    size_t dst = ((size_t)b * 32 + m) * 1024 + n * 128 + i;  // [b][m][d]
    Or[dst] = vr; Oi[dst] = vi;
  }
}

// ---------------- kernel D3: d-chunked irfft + residual in-place ----------------
// grid 2048 = b(4) x tchunk(64, 64 t each) x dchunk(8, 128 d each); block 256.
// LDS stagger phys(w) = w + ((w>>5)<<2): the 16 per-lane b128 addresses hit 16
// distinct bank-quads (2-way = free).
__global__ __launch_bounds__(256) void kernelD3(const float* __restrict__ Or, const float* __restrict__ Oi,
    const float* __restrict__ ctab, const float* __restrict__ stab, float* __restrict__ y){
  __shared__ float cts[32][64], sts[32][64];
  __shared__ float Ors[32][144], Ois[32][144];
  int tid = threadIdx.x;
  int bx = blockIdx.x;
  int b = bx >> 9, tc = (bx >> 3) & 63, dc = bx & 7;
  int t0 = tc * 64, d0 = dc * 128;
  for (int i = 0; i < 8; ++i){
    int lin = i * 256 + tid;            // 2048 = 32 m x 64 t
    int m = lin >> 6, tl = lin & 63;
    float f = (m == 0 ? 1.0f : 2.0f) * 0.015625f;  // irfft ortho scale
    cts[m][tl] = ctab[m * 4096 + t0 + tl] * f;
    sts[m][tl] = stab[m * 4096 + t0 + tl] * f;     // sts[0][*]=0 -> mode-0 imag ignored
  }
  for (int i = 0; i < 4; ++i){
    int lin = i * 256 + tid;            // 1024 = 32 m x 32 quads
    int m = lin >> 5, q = lin & 31;
    int w = q * 4;
    int ph = w + ((w >> 5) << 2);
    size_t src = ((size_t)b * 32 + m) * 1024 + d0 + w;
    *(f32x4*)&Ors[m][ph] = *(const f32x4*)&Or[src];
    *(f32x4*)&Ois[m][ph] = *(const f32x4*)&Oi[src];
  }
  __syncthreads();
  int tt = tid >> 4, dl = tid & 15;     // 4 t per thread, 8 d per thread
  int wb0 = dl * 8;
  int ph0 = wb0 + ((wb0 >> 5) << 2);
  int ph1 = ph0 + 4;
  float acc[4][8];
  #pragma unroll
  for (int q = 0; q < 4; ++q)
    #pragma unroll
    for (int j = 0; j < 8; ++j) acc[q][j] = 0.f;
  for (int m = 0; m < 32; ++m){
    f32x4 cv = *(const f32x4*)&cts[m][tt * 4];
    f32x4 sv = *(const f32x4*)&sts[m][tt * 4];
    f32x4 orv0 = *(const f32x4*)&Ors[m][ph0];
    f32x4 orv1 = *(const f32x4*)&Ors[m][ph1];
    f32x4 oiv0 = *(const f32x4*)&Ois[m][ph0];
    f32x4 oiv1 = *(const f32x4*)&Ois[m][ph1];
    #pragma unroll
    for (int q = 0; q < 4; ++q){
      #pragma unroll
      for (int e = 0; e < 4; ++e){
        acc[q][e]     += cv[q] * orv0[e] - sv[q] * oiv0[e];
        acc[q][4 + e] += cv[q] * orv1[e] - sv[q] * oiv1[e];
      }
    }
  }
  #pragma unroll
  for (int q = 0; q < 4; ++q){
    size_t row = ((size_t)b * 4096 + t0 + tt * 4 + q) * 1024 + d0 + dl * 8;
    f32x4 r0 = *(const f32x4*)&y[row];
    f32x4 r1 = *(const f32x4*)&y[row + 4];
    #pragma unroll
    for (int e = 0; e < 4; ++e){ r0[e] += acc[q][e]; r1[e] += acc[q][4 + e]; }
    *(f32x4*)&y[row] = r0;
    *(f32x4*)&y[row + 4] = r1;
  }
}

// ---------------- LN1: y (f32) -> xln1 (bf16) ----------------
__global__ __launch_bounds__(256) void ln1_k(const float* __restrict__ y,
    const float* __restrict__ g, const float* __restrict__ bb, short* __restrict__ xln){
  size_t row = blockIdx.x;
  int tid = threadIdx.x;
  f32x4 v = *(const f32x4*)(y + row * 1024 + tid * 4);
  float sum = v[0] + v[1] + v[2] + v[3];
  float sq  = v[0]*v[0] + v[1]*v[1] + v[2]*v[2] + v[3]*v[3];
  for (int off = 32; off; off >>= 1){ sum += __shfl_down(sum, off); sq += __shfl_down(sq, off); }
  __shared__ float rs[4], rq[4];
  int lane = tid & 63, w = tid >> 6;
  if (lane == 0){ rs[w] = sum; rq[w] = sq; }
  __syncthreads();
  sum = rs[0] + rs[1] + rs[2] + rs[3]; sq = rq[0] + rq[1] + rq[2] + rq[3];
  float mu = sum * (1.0f / 1024.0f);
  float var = sq * (1.0f / 1024.0f) - mu * mu;
  float sc = rsqrtf(var + 1e-5f);
  s16x4 o;
  #pragma unroll
  for (int j = 0; j < 4; ++j){
    int d = tid * 4 + j;
    o[j] = f2bf((v[j] - mu) * sc * g[d] + bb[d]);
  }
  *(s16x4*)(xln + row * 1024 + tid * 4) = o;
}

// ---------------- per-quadrant-phase pipelined bf16 MFMA GEMM ----------------
template<int CFG, int EPI>
__global__ __launch_bounds__(512, 2) void gemm8p_k(const short* __restrict__ A,
    const short* __restrict__ BT, const float* __restrict__ bias,
    const short* __restrict__ resid, short* __restrict__ Hout,
    float* __restrict__ Fout, int K, int N, long row0_abs, int nMB){
  constexpr int BN = (CFG == 0) ? 256 : 128;
  constexpr int NI = (CFG == 0) ? 4 : 2;
  __shared__ __align__(16) short As[2][256 * 64];
  __shared__ __align__(16) short Bs[2][BN * 64];
  const int tid = threadIdx.x;
  const int lane = tid & 63, wv = tid >> 6;
  const int wr = wv >> 2, wc = wv & 3;
  const int lr = lane & 15, lg = lane >> 4;
  const int wrlr = wr * 16 + lr;

  int nwg = gridDim.x;
  int flat = blockIdx.x;
  int swz = (flat & 7) * (nwg >> 3) + (flat >> 3);
  int mb = swz % nMB, nb = swz / nMB;
  const long arow0 = (long)mb * 256;
  const long bcol0 = (long)nb * BN;
  const int NT = K >> 6;

  auto stageA = [&](int t, int h){
    short* dst = &As[t & 1][h * 128 * 64];
    const short* src = A + (arow0 + h * 128) * (long)K + (long)t * 64;
    #pragma unroll
    for (int u = 0; u < 2; ++u){
      int idx = u * 512 + tid;
      int r = idx >> 3, sl = (idx & 7) ^ (r & 7);
      gload16(src + (long)r * K + sl * 8, dst + (u * 512 + wv * 64) * 8);
    }
  };
  auto stageB = [&](int t, int h){
    short* dst = &Bs[t & 1][h * 128 * 64];
    const short* src = BT + (bcol0 + h * 128) * (long)K + (long)t * 64;
    #pragma unroll
    for (int u = 0; u < 2; ++u){
      int idx = u * 512 + tid;
      int r = idx >> 3, sl = (idx & 7) ^ (r & 7);
      gload16(src + (long)r * K + sl * 8, dst + (u * 512 + wv * 64) * 8);
    }
  };

  f32x4 acc[8][NI] = {};
  s16x8 af[4][2], bfl[2][2], bfh[2][2];

  auto loadA4 = [&](const short* as, int mib){
    #pragma unroll
    for (int mi = 0; mi < 4; ++mi)
      #pragma unroll
      for (int ks = 0; ks < 2; ++ks){
        int R = (mib + mi) * 32 + wrlr;
        af[mi][ks] = *(const s16x8*)&as[R * 64 + (((ks * 4 + lg) ^ (R & 7)) << 3)];
      }
  };
  auto loadB2 = [&](const short* bs, s16x8 (&bf)[2][2], int nib){
    #pragma unroll
    for (int ni = 0; ni < 2; ++ni)
      #pragma unroll
      for (int ks = 0; ks < 2; ++ks){
        int R = (CFG == 0) ? ((nib + ni) * 64 + wc * 16 + lr)
                           : (wc * 32 + (nib + ni) * 16 + lr);
        bf[ni][ks] = *(const s16x8*)&bs[R * 64 + (((ks * 4 + lg) ^ (R & 7)) << 3)];
      }
  };
  auto mfmaQ = [&](s16x8 (&bf)[2][2], int mib, int nib){
    __builtin_amdgcn_s_setprio(1);
    #pragma unroll
    for (int ks = 0; ks < 2; ++ks)
      #pragma unroll
      for (int mi = 0; mi < 4; ++mi)
        #pragma unroll
        for (int ni = 0; ni < 2; ++ni)
          acc[mib + mi][nib + ni] = __builtin_amdgcn_mfma_f32_16x16x32_bf16(
              af[mi][ks], bf[ni][ks], acc[mib + mi][nib + ni], 0, 0, 0);
    __builtin_amdgcn_s_setprio(0);
  };

  if constexpr (CFG == 0){
    stageA(0,0); stageB(0,1); stageB(0,0); stageA(0,1); stageA(1,0); stageB(1,1);
    VM(6); SCHED0; BARR; SCHED0;
    for (int t = 0; t < NT; ++t){
      const short* as = As[t & 1];
      const short* bs = Bs[t & 1];
      const bool s1 = (t + 1 < NT), s2 = (t + 2 < NT);
      loadA4(as, 0); loadB2(bs, bfl, 0);
      SCHED0; if (s1) stageB(t + 1, 0); SCHED0;
      BARR;
      mfmaQ(bfl, 0, 0);
      SCHED0; LGKM0; SCHED0; BARR; SCHED0;
      loadB2(bs, bfh, 2);
      SCHED0; if (s1) stageA(t + 1, 1); SCHED0;
      BARR;
      mfmaQ(bfh, 0, 2);
      SCHED0; LGKM0;
      if (s1) { VM(8); } else { VM(0); }
      SCHED0; BARR; SCHED0;
      loadA4(as, 4);
      SCHED0; if (s2) stageA(t + 2, 0); SCHED0;
      BARR;
      mfmaQ(bfl, 4, 0);
      SCHED0; LGKM0; SCHED0; BARR; SCHED0;
      SCHED0; if (s2) stageB(t + 2, 1); SCHED0;
      BARR;
      mfmaQ(bfh, 4, 2);
      SCHED0;
      if (s1) { if (s2) { VM(6); } else { VM(2); } }
      SCHED0; BARR; SCHED0;
    }
  } else {
    stageA(0,0); stageB(0,0); stageA(0,1); stageA(1,0); stageB(1,0);
    VM(6); SCHED0; BARR; SCHED0;
    for (int t = 0; t < NT; ++t){
      const short* as = As[t & 1];
      const short* bs = Bs[t & 1];
      const bool s1 = (t + 1 < NT), s2 = (t + 2 < NT);
      loadA4(as, 0); loadB2(bs, bfl, 0);
      SCHED0; if (s1) stageA(t + 1, 1); SCHED0;
      BARR;
      mfmaQ(bfl, 0, 0);
      SCHED0; LGKM0;
      if (s1) { VM(6); } else { VM(0); }
      SCHED0; BARR; SCHED0;
      loadA4(as, 4);
      SCHED0; if (s2) { stageA(t + 2, 0); stageB(t + 2, 0); } SCHED0;
      BARR;
      mfmaQ(bfl, 4, 0);
      SCHED0; LGKM0;
      if (s1) { if (s2) { VM(6); } else { VM(2); } }
      SCHED0; BARR; SCHED0;
    }
  }

  SCHED0;
  const int rb = lg * 4;
  #pragma unroll
  for (int mi = 0; mi < 8; ++mi){
    #pragma unroll
    for (int ni = 0; ni < NI; ++ni){
      int cl = (int)bcol0 + ((CFG == 0) ? (ni * 64 + wc * 16 + lr)
                                        : (wc * 32 + ni * 16 + lr));
      float bv = bias[cl];
      #pragma unroll
      for (int i = 0; i < 4; ++i){
        long rl = arow0 + mi * 32 + wr * 16 + rb + i;
        float v = acc[mi][ni][i] + bv;
        if constexpr (EPI == 0){
          Hout[rl * (long)N + cl] = f2bf(gelu_f(v));
        } else {
          float rr = bf2f(resid[(row0_abs + rl) * 1024 + cl]);
          Fout[(row0_abs + rl) * 1024 + cl] = v + rr;
        }
      }
    }
  }
}

// ---------------- LN2 in-place on f32 out ----------------
__global__ __launch_bounds__(256) void ln2_k(float* __restrict__ out,
    const float* __restrict__ g, const float* __restrict__ bb){
  size_t row = blockIdx.x;
  int tid = threadIdx.x;
  float* p = out + row * 1024;
  f32x4 v = *(const f32x4*)(p + tid * 4);
  float sum = v[0] + v[1] + v[2] + v[3];
  float sq  = v[0]*v[0] + v[1]*v[1] + v[2]*v[2] + v[3]*v[3];
  for (int off = 32; off; off >>= 1){ sum += __shfl_down(sum, off); sq += __shfl_down(sq, off); }
  __shared__ float rs[4], rq[4];
  int lane = tid & 63, w = tid >> 6;
  if (lane == 0){ rs[w] = sum; rq[w] = sq; }
  __syncthreads();
  sum = rs[0] + rs[1] + rs[2] + rs[3]; sq = rq[0] + rq[1] + rq[2] + rq[3];
  float mu = sum * (1.0f / 1024.0f);
  float var = sq * (1.0f / 1024.0f) - mu * mu;
  float sc = rsqrtf(var + 1e-5f);
  f32x4 o;
  #pragma unroll
  for (int j = 0; j < 4; ++j){
    int d = tid * 4 + j;
    o[j] = (v[j] - mu) * sc * g[d] + bb[d];
  }
  *(f32x4*)(p + tid * 4) = o;
}

// ---------------- launch ----------------
extern "C" void kernel_launch(void* const* d_in, const int* in_sizes, int n_in,
                              void* d_out, int out_size, void* d_ws, size_t ws_size,
                              hipStream_t stream){
  (void)in_sizes; (void)n_in; (void)out_size; (void)ws_size;
  const int*   tokens = (const int*)d_in[0];
  const float* frw  = (const float*)d_in[1];
  const float* fiw  = (const float*)d_in[2];
  const float* mw   = (const float*)d_in[3];
  const float* po   = (const float*)d_in[4];
  const float* ftew = (const float*)d_in[5];
  const float* fteb = (const float*)d_in[6];
  const float* posph= (const float*)d_in[7];
  const float* awr  = (const float*)d_in[8];
  const float* awi  = (const float*)d_in[9];
  const float* ln1g = (const float*)d_in[10];
  const float* ln1b = (const float*)d_in[11];
  const float* w1   = (const float*)d_in[12];
  const float* b1   = (const float*)d_in[13];
  const float* w2   = (const float*)d_in[14];
  const float* b2   = (const float*)d_in[15];
  const float* ln2g = (const float*)d_in[16];
  const float* ln2b = (const float*)d_in[17];
  float* out = (float*)d_out;

  char* ws = (char*)d_ws;
  size_t o = 0;
  float* residual = (float*)(ws + o); o += (size_t)16384 * 1024 * 4;  // 67.1 MB; later hbuf
  short* xln1     = (short*)(ws + o); o += (size_t)16384 * 1024 * 2;  // 33.6 MB
  short* w1b      = (short*)(ws + o); o += (size_t)4096 * 1024 * 2;
  short* w2b      = (short*)(ws + o); o += (size_t)4096 * 1024 * 2;
  float* ctab     = (float*)(ws + o); o += 524288;
  float* stab     = (float*)(ws + o); o += 524288;
  float* Xr       = (float*)(ws + o); o += 524288;
  float* Xi       = (float*)(ws + o); o += 524288;
  float* Or       = (float*)(ws + o); o += 524288;
  float* Oi       = (float*)(ws + o); o += 524288;
  float* Pr       = (float*)(ws + o); o += (size_t)8 * 4 * 1024 * 32 * 4;
  float* Pi       = (float*)(ws + o); o += (size_t)8 * 4 * 1024 * 32 * 4;
  float* wcs      = (float*)(ws + o); o += 512;
  short* hbuf     = (short*)residual;   // 8192x4096 bf16 aliases dead residual

  prep_wcs_k<<<1, 64, 0, stream>>>(mw, po, wcs);
  prep_tab_k<<<512, 256, 0, stream>>>(ctab, stab);
  transpose_bf16_k<<<dim3(64, 16), 256, 0, stream>>>(w1, w1b, 1024, 4096);
  transpose_bf16_k<<<dim3(16, 64), 256, 0, stream>>>(w2, w2b, 4096, 1024);

  kernelA<<<4096, 256, 0, stream>>>(tokens, frw, fiw, wcs, ftew, fteb, posph, residual);
  kernelB2<<<1024, 256, 0, stream>>>(residual, Pr, Pi);
  reduceB_k<<<512, 256, 0, stream>>>(Pr, Pi, Xr, Xi);
  kernelC<<<256, 128, 0, stream>>>(Xr, Xi, awr, awi, Or, Oi);
  kernelD3<<<2048, 256, 0, stream>>>(Or, Oi, ctab, stab, residual);
  ln1_k<<<16384, 256, 0, stream>>>(residual, ln1g, ln1b, xln1);

  for (int c = 0; c < 2; ++c){
    long row0 = (long)c * 8192;
    gemm8p_k<0, 0><<<512, 512, 0, stream>>>(xln1 + row0 * 1024, w1b, b1,
                                            nullptr, hbuf, nullptr, 1024, 4096, 0, 32);
    gemm8p_k<1, 1><<<256, 512, 0, stream>>>(hbuf, w2b, b2,
                                            xln1, nullptr, out, 4096, 1024, row0, 32);
  }
  ln2_k<<<16384, 256, 0, stream>>>(out, ln2g, ln2b);
}

// Round 6
// 561.547 us; speedup vs baseline: 1.8148x; 1.0442x over previous
//
#include <hip/hip_runtime.h>

// WaveInputEncoder on MI355X — round 6.
// vs r5: GEMM K-loop restructured to ONE barrier per phase (true T3 overlap:
// reads_{p+1} of some waves run under MFMA_p of others). CFG1 -> 4Mx2N waves,
// A 3-buffer + B 2-buffer, 4-phase, steady VM(4). Per-XCD compact block tiles.

typedef __attribute__((ext_vector_type(8))) short s16x8;
typedef __attribute__((ext_vector_type(4))) short s16x4;
typedef __attribute__((ext_vector_type(4))) float f32x4;

#define SCHED0 __builtin_amdgcn_sched_barrier(0)
#define BARR   __builtin_amdgcn_s_barrier()
#define LGKM0  asm volatile("s_waitcnt lgkmcnt(0)" ::: "memory")
#define VM(n)  asm volatile("s_waitcnt vmcnt(" #n ")" ::: "memory")

__device__ __forceinline__ short f2bf(float x){
  unsigned u = __float_as_uint(x);
  unsigned r = (u + 0x7fffu + ((u >> 16) & 1u)) >> 16;   // RNE
  return (short)r;
}
__device__ __forceinline__ float bf2f(short x){
  return __uint_as_float(((unsigned)(unsigned short)x) << 16);
}
__device__ __forceinline__ void gload16(const void* g, void* l){
  __builtin_amdgcn_global_load_lds((const __attribute__((address_space(1))) void*)g,
                                   (__attribute__((address_space(3))) void*)l, 16, 0, 0);
}
__device__ __forceinline__ float gelu_f(float v){
  float u2 = v * (0.7978845608f + 0.0356774081f * v * v);
  float e = __expf(2.0f * u2);
  float th = 1.0f - 2.0f / (e + 1.0f);
  return 0.5f * v * (1.0f + th);
}

// ---------------- prep kernels ----------------
__global__ void prep_wcs_k(const float* __restrict__ mw, const float* __restrict__ po,
                           float* __restrict__ wcs){
  int i = threadIdx.x;
  if (i < 32){
    wcs[i]      = log1pf(expf(mw[i]));  // softplus
    wcs[32 + i] = cosf(po[i]);
    wcs[64 + i] = sinf(po[i]);
  }
}

__global__ __launch_bounds__(256) void prep_tab_k(float* __restrict__ ctab, float* __restrict__ stab){
  int idx = blockIdx.x * 256 + threadIdx.x;      // idx = m*4096 + t
  int m = idx >> 12, t = idx & 4095;
  int r = (m * t) & 4095;
  float ang = (float)r * 1.5339807878856412e-3f; // 2*pi/4096
  float s, c; sincosf(ang, &s, &c);
  ctab[idx] = c; stab[idx] = s;
}

// transpose fp32 (R x C) -> bf16 (C x R), 64x64 LDS tiles
__global__ __launch_bounds__(256) void transpose_bf16_k(const float* __restrict__ src,
                                                        short* __restrict__ dst,
                                                        int R, int C){
  __shared__ float tile[64][65];
  int c0 = blockIdx.x * 64, r0 = blockIdx.y * 64;
  for (int i = 0; i < 16; ++i){
    int idx = i * 256 + threadIdx.x;
    int rr = idx >> 6, cc = idx & 63;
    tile[rr][cc] = src[(size_t)(r0 + rr) * C + c0 + cc];
  }
  __syncthreads();
  for (int i = 0; i < 16; ++i){
    int idx = i * 256 + threadIdx.x;
    int cc = idx >> 6, rr = idx & 63;
    dst[(size_t)(c0 + cc) * R + r0 + rr] = f2bf(tile[rr][cc]);
  }
}

// ---------------- kernel A ----------------
__global__ __launch_bounds__(256) void kernelA(const int* __restrict__ tokens,
    const float* __restrict__ frw, const float* __restrict__ fiw,
    const float* __restrict__ wcs, const float* __restrict__ ftew,
    const float* __restrict__ fteb, const float* __restrict__ posph,
    float* __restrict__ xout){
  __shared__ float ffs[4][64];
  __shared__ float xs[4][1024];
  __shared__ float wsh[96];
  int tid = threadIdx.x;
  int b = blockIdx.x >> 10, t0 = (blockIdx.x & 1023) * 4;
  if (tid < 96) wsh[tid] = wcs[tid];
  __syncthreads();
  if (tid < 128){
    int tk = tid >> 5, m = tid & 31;
    int tok = tokens[b * 4096 + t0 + tk];
    float w = wsh[m];
    float re = frw[(size_t)tok * 32 + m] * w;
    float im = fiw[(size_t)tok * 32 + m] * w;
    float c = wsh[32 + m], s = wsh[64 + m];
    ffs[tk][m]      = re * c - im * s;
    ffs[tk][32 + m] = re * s + im * c;
  }
  __syncthreads();
  for (int p = 0; p < 4; ++p){
    int dd = p * 256 + tid;
    float bb = fteb[dd];
    float a0 = bb, a1 = bb, a2 = bb, a3 = bb;
    #pragma unroll 8
    for (int k = 0; k < 64; ++k){
      float wv = ftew[k * 1024 + dd];
      a0 += ffs[0][k] * wv; a1 += ffs[1][k] * wv;
      a2 += ffs[2][k] * wv; a3 += ffs[3][k] * wv;
    }
    xs[0][dd] = a0; xs[1][dd] = a1; xs[2][dd] = a2; xs[3][dd] = a3;
  }
  __syncthreads();
  for (int p = 0; p < 4; ++p){
    int dd = p * 256 + tid, dm = (dd + 1023) & 1023;
    #pragma unroll
    for (int tk = 0; tk < 4; ++tk){
      float pp = posph[(size_t)(t0 + tk) * 1024 + dd];
      float p2 = pp * pp;
      float sp = pp * (1.0f - p2 * (1.0f/6.0f) + p2 * p2 * (1.0f/120.0f));
      float cp = 1.0f - p2 * 0.5f + p2 * p2 * (1.0f/24.0f);
      xout[((size_t)b * 4096 + t0 + tk) * 1024 + dd] = xs[tk][dd] * cp + xs[tk][dm] * sp;
    }
  }
}

// ---------------- kernel B: truncated forward DFT via rotation recurrence ----------------
__global__ __launch_bounds__(256) void kernelB2(const float* __restrict__ xin,
    float* __restrict__ Pr, float* __restrict__ Pi){
  __shared__ float xsh[64][32];
  int tid = threadIdx.x;
  int bx = blockIdx.x;
  int b = bx >> 8, dch = (bx >> 3) & 31, tc = bx & 7;
  int d0 = dch * 32;
  int t_start = tc * 512;
  int dg = tid >> 5, m = tid & 31;
  const float TPN = 1.5339807878856412e-3f;
  int r0 = (m * t_start) & 4095;
  float cw, sw; sincosf(-(float)r0 * TPN, &sw, &cw);
  float cs, ss; sincosf(-(float)m * TPN, &ss, &cs);
  float ar[4] = {0,0,0,0}, ai[4] = {0,0,0,0};
  for (int t0 = t_start; t0 < t_start + 512; t0 += 64){
    __syncthreads();
    #pragma unroll
    for (int i = 0; i < 2; ++i){
      int unit = i * 256 + tid;
      int tt = unit >> 3, du = (unit & 7) * 4;
      *(f32x4*)&xsh[tt][du] = *(const f32x4*)&xin[((size_t)b * 4096 + t0 + tt) * 1024 + d0 + du];
    }
    __syncthreads();
    #pragma unroll 4
    for (int tt = 0; tt < 64; ++tt){
      f32x4 xv = *(const f32x4*)&xsh[tt][dg * 4];
      #pragma unroll
      for (int j = 0; j < 4; ++j){ ar[j] += xv[j] * cw; ai[j] += xv[j] * sw; }
      float cn = cw * cs - sw * ss;
      sw = cw * ss + sw * cs; cw = cn;
    }
  }
  #pragma unroll
  for (int j = 0; j < 4; ++j){
    int d = d0 + dg * 4 + j;
    size_t idx = (((size_t)tc * 4 + b) * 1024 + d) * 32 + m;
    Pr[idx] = ar[j]; Pi[idx] = ai[j];
  }
}

__global__ __launch_bounds__(256) void reduceB_k(const float* __restrict__ Pr,
    const float* __restrict__ Pi, float* __restrict__ Xr, float* __restrict__ Xi){
  int lin = blockIdx.x * 256 + threadIdx.x;
  int m = lin & 31, d = (lin >> 5) & 1023, b = lin >> 15;
  float sr = 0.0f, si = 0.0f;
  for (int tc = 0; tc < 8; ++tc){
    size_t idx = (((size_t)tc * 4 + b) * 1024 + d) * 32 + m;
    sr += Pr[idx]; si += Pi[idx];
  }
  int n = d >> 7, jj = d & 127;
  size_t o = (((size_t)b * 8 + n) * 32 + m) * 128 + jj;
  Xr[o] = sr * 0.015625f; Xi[o] = si * 0.015625f;
}

// ---------------- kernel C ----------------
__global__ __launch_bounds__(128) void kernelC(const float* __restrict__ Xr, const float* __restrict__ Xi,
    const float* __restrict__ awr, const float* __restrict__ awi,
    float* __restrict__ Or, float* __restrict__ Oi){
  __shared__ float xr_s[4][128], xi_s[4][128];
  int nm = blockIdx.x; int n = nm >> 5, m = nm & 31;
  int i = threadIdx.x;
  for (int b = 0; b < 4; ++b){
    size_t src = (((size_t)b * 8 + n) * 32 + m) * 128 + i;
    xr_s[b][i] = Xr[src]; xi_s[b][i] = Xi[src];
  }
  __syncthreads();
  float accr[4] = {0,0,0,0}, acci[4] = {0,0,0,0};
  size_t wb = (((size_t)n * 32 + m) * 128 + i) * 128;
  for (int j = 0; j < 128; ++j){
    float wr = awr[wb + j], wi = awi[wb + j];
    #pragma unroll
    for (int b = 0; b < 4; ++b){
      accr[b] += wr * xr_s[b][j] - wi * xi_s[b][j];
      acci[b] += wr * xi_s[b][j] + wi * xr_s[b][j];
    }
  }
  #pragma unroll
  for (int b = 0; b < 4; ++b){
    float vr = accr[b], vi = acci[b];
    vr = vr > 0.01f ? vr - 0.01f : (vr < -0.01f ? vr + 0.01f : 0.0f);
    vi = vi > 0.01f ? vi - 0.01f : (vi < -0.01f ? vi + 0.01f : 0.0f);
    size_t dst = ((size_t)b * 32 + m) * 1024 + n * 128 + i;  // [b][m][d]
    Or[dst] = vr; Oi[dst] = vi;
  }
}

// ---------------- kernel D3: d-chunked irfft + residual in-place ----------------
__global__ __launch_bounds__(256) void kernelD3(const float* __restrict__ Or, const float* __restrict__ Oi,
    const float* __restrict__ ctab, const float* __restrict__ stab, float* __restrict__ y){
  __shared__ float cts[32][64], sts[32][64];
  __shared__ float Ors[32][144], Ois[32][144];
  int tid = threadIdx.x;
  int bx = blockIdx.x;
  int b = bx >> 9, tc = (bx >> 3) & 63, dc = bx & 7;
  int t0 = tc * 64, d0 = dc * 128;
  for (int i = 0; i < 8; ++i){
    int lin = i * 256 + tid;
    int m = lin >> 6, tl = lin & 63;
    float f = (m == 0 ? 1.0f : 2.0f) * 0.015625f;
    cts[m][tl] = ctab[m * 4096 + t0 + tl] * f;
    sts[m][tl] = stab[m * 4096 + t0 + tl] * f;
  }
  for (int i = 0; i < 4; ++i){
    int lin = i * 256 + tid;
    int m = lin >> 5, q = lin & 31;
    int w = q * 4;
    int ph = w + ((w >> 5) << 2);
    size_t src = ((size_t)b * 32 + m) * 1024 + d0 + w;
    *(f32x4*)&Ors[m][ph] = *(const f32x4*)&Or[src];
    *(f32x4*)&Ois[m][ph] = *(const f32x4*)&Oi[src];
  }
  __syncthreads();
  int tt = tid >> 4, dl = tid & 15;
  int wb0 = dl * 8;
  int ph0 = wb0 + ((wb0 >> 5) << 2);
  int ph1 = ph0 + 4;
  float acc[4][8];
  #pragma unroll
  for (int q = 0; q < 4; ++q)
    #pragma unroll
    for (int j = 0; j < 8; ++j) acc[q][j] = 0.f;
  for (int m = 0; m < 32; ++m){
    f32x4 cv = *(const f32x4*)&cts[m][tt * 4];
    f32x4 sv = *(const f32x4*)&sts[m][tt * 4];
    f32x4 orv0 = *(const f32x4*)&Ors[m][ph0];
    f32x4 orv1 = *(const f32x4*)&Ors[m][ph1];
    f32x4 oiv0 = *(const f32x4*)&Ois[m][ph0];
    f32x4 oiv1 = *(const f32x4*)&Ois[m][ph1];
    #pragma unroll
    for (int q = 0; q < 4; ++q){
      #pragma unroll
      for (int e = 0; e < 4; ++e){
        acc[q][e]     += cv[q] * orv0[e] - sv[q] * oiv0[e];
        acc[q][4 + e] += cv[q] * orv1[e] - sv[q] * oiv1[e];
      }
    }
  }
  #pragma unroll
  for (int q = 0; q < 4; ++q){
    size_t row = ((size_t)b * 4096 + t0 + tt * 4 + q) * 1024 + d0 + dl * 8;
    f32x4 r0 = *(const f32x4*)&y[row];
    f32x4 r1 = *(const f32x4*)&y[row + 4];
    #pragma unroll
    for (int e = 0; e < 4; ++e){ r0[e] += acc[q][e]; r1[e] += acc[q][4 + e]; }
    *(f32x4*)&y[row] = r0;
    *(f32x4*)&y[row + 4] = r1;
  }
}

// ---------------- LN1: y (f32) -> xln1 (bf16) ----------------
__global__ __launch_bounds__(256) void ln1_k(const float* __restrict__ y,
    const float* __restrict__ g, const float* __restrict__ bb, short* __restrict__ xln){
  size_t row = blockIdx.x;
  int tid = threadIdx.x;
  f32x4 v = *(const f32x4*)(y + row * 1024 + tid * 4);
  float sum = v[0] + v[1] + v[2] + v[3];
  float sq  = v[0]*v[0] + v[1]*v[1] + v[2]*v[2] + v[3]*v[3];
  for (int off = 32; off; off >>= 1){ sum += __shfl_down(sum, off); sq += __shfl_down(sq, off); }
  __shared__ float rs[4], rq[4];
  int lane = tid & 63, w = tid >> 6;
  if (lane == 0){ rs[w] = sum; rq[w] = sq; }
  __syncthreads();
  sum = rs[0] + rs[1] + rs[2] + rs[3]; sq = rq[0] + rq[1] + rq[2] + rq[3];
  float mu = sum * (1.0f / 1024.0f);
  float var = sq * (1.0f / 1024.0f) - mu * mu;
  float sc = rsqrtf(var + 1e-5f);
  s16x4 o;
  #pragma unroll
  for (int j = 0; j < 4; ++j){
    int d = tid * 4 + j;
    o[j] = f2bf((v[j] - mu) * sc * g[d] + bb[d]);
  }
  *(s16x4*)(xln + row * 1024 + tid * 4) = o;
}

// ---------------- one-barrier-per-phase pipelined bf16 MFMA GEMM ----------------
// CFG0: BM=256 BN=256, waves 2Mx4N, 4 phases/K-tile, A/B double-buffered.
// CFG1: BM=256 BN=128, waves 4Mx2N, 4 phases/K-tile, A triple-, B double-buffered.
// Block body per phase: [reads; stage; (VM); SCHED0; BARR; lgkm0; SCHED0; MFMA]
// -> reads_{p+1} of leading waves overlap MFMA_p of lagging waves.
template<int CFG, int EPI>
__global__ __launch_bounds__(512, 2) void gemm8p_k(const short* __restrict__ A,
    const short* __restrict__ BT, const float* __restrict__ bias,
    const short* __restrict__ resid, short* __restrict__ Hout,
    float* __restrict__ Fout, int K, int N, long row0_abs){
  constexpr int BN = (CFG == 0) ? 256 : 128;
  constexpr int MI = (CFG == 0) ? 8 : 4;
  constexpr int NI = 4;
  constexpr int NAB = (CFG == 0) ? 2 : 3;              // A buffers
  __shared__ __align__(16) short AsM[NAB * 256 * 64];
  __shared__ __align__(16) short BsM[2 * BN * 64];
  const int tid = threadIdx.x;
  const int lane = tid & 63, wv = tid >> 6;
  const int wr = (CFG == 0) ? (wv >> 2) : (wv >> 1);
  const int wc = (CFG == 0) ? (wv & 3) : (wv & 1);
  const int lr = lane & 15, lg = lane >> 4;

  // per-XCD compact block tile (L2 locality): CFG0 grid 512 -> 8 XCD x (8mb x 8nb);
  // CFG1 grid 256 -> 8 XCD x (8mb x 4nb)
  int flat = blockIdx.x;
  int xcd = flat & 7, l = flat >> 3;
  int mb = (xcd & 3) * 8 + (l & 7);
  int nb = (CFG == 0) ? ((xcd >> 2) * 8 + (l >> 3)) : ((xcd >> 2) * 4 + (l >> 3));
  const long arow0 = (long)mb * 256;
  const long bcol0 = (long)nb * BN;
  const int NT = K >> 6;

  auto stageA = [&](int buf, int h, long kof){
    short* dst = &AsM[buf * (256 * 64) + h * (128 * 64)];
    const short* src = A + (arow0 + h * 128) * (long)K + kof;
    #pragma unroll
    for (int u = 0; u < 2; ++u){
      int idx = u * 512 + tid;
      int r = idx >> 3, sl = (idx & 7) ^ (r & 7);
      gload16(src + (long)r * K + sl * 8, dst + (u * 512 + wv * 64) * 8);
    }
  };
  auto stageB = [&](int buf, int h, long kof){
    short* dst = &BsM[buf * (BN * 64) + h * (128 * 64)];
    const short* src = BT + (bcol0 + h * 128) * (long)K + kof;
    #pragma unroll
    for (int u = 0; u < 2; ++u){
      int idx = u * 512 + tid;
      int r = idx >> 3, sl = (idx & 7) ^ (r & 7);
      gload16(src + (long)r * K + sl * 8, dst + (u * 512 + wv * 64) * 8);
    }
  };

  f32x4 acc[MI][NI] = {};

  if constexpr (CFG == 0){
    s16x8 af[4][2], bfl[2][2], bfh[2][2];
    auto loadA4 = [&](const short* as, int mib){
      #pragma unroll
      for (int mi = 0; mi < 4; ++mi)
        #pragma unroll
        for (int ks = 0; ks < 2; ++ks){
          int R = (mib + mi) * 32 + wr * 16 + lr;
          af[mi][ks] = *(const s16x8*)&as[R * 64 + (((ks * 4 + lg) ^ (R & 7)) << 3)];
        }
    };
    auto loadB2 = [&](const short* bs, s16x8 (&bf)[2][2], int nib){
      #pragma unroll
      for (int ni = 0; ni < 2; ++ni)
        #pragma unroll
        for (int ks = 0; ks < 2; ++ks){
          int R = (nib + ni) * 64 + wc * 16 + lr;
          bf[ni][ks] = *(const s16x8*)&bs[R * 64 + (((ks * 4 + lg) ^ (R & 7)) << 3)];
        }
    };
    auto mfmaQ = [&](s16x8 (&bf)[2][2], int mib, int nib){
      __builtin_amdgcn_s_setprio(1);
      #pragma unroll
      for (int ks = 0; ks < 2; ++ks)
        #pragma unroll
        for (int mi = 0; mi < 4; ++mi)
          #pragma unroll
          for (int ni = 0; ni < 2; ++ni)
            acc[mib + mi][nib + ni] = __builtin_amdgcn_mfma_f32_16x16x32_bf16(
                af[mi][ks], bf[ni][ks], acc[mib + mi][nib + ni], 0, 0, 0);
      __builtin_amdgcn_s_setprio(0);
    };

    // prologue: A0(0), B1(0), B0(0), A1(0), A0(1), B1(1)
    stageA(0,0,0); stageB(0,1,0); stageB(0,0,0); stageA(0,1,0);
    stageA(1,0,64); stageB(1,1,64);
    VM(6); SCHED0; BARR; SCHED0;
    for (int t = 0; t < NT; ++t){
      const short* as = &AsM[(t & 1) * (256 * 64)];
      const short* bs = &BsM[(t & 1) * (256 * 64)];
      const bool s1 = (t + 1 < NT), s2 = (t + 2 < NT);
      // q0
      loadA4(as, 0); loadB2(bs, bfl, 0);
      if (s1) stageB((t + 1) & 1, 0, (long)(t + 1) * 64);
      SCHED0; BARR; LGKM0; SCHED0;
      mfmaQ(bfl, 0, 0);
      // q1
      loadB2(bs, bfh, 2);
      if (s1) stageA((t + 1) & 1, 1, (long)(t + 1) * 64);
      if (s1) { VM(8); } else { VM(0); }
      SCHED0; BARR; LGKM0; SCHED0;
      mfmaQ(bfh, 0, 2);
      // q2
      loadA4(as, 4);
      if (s2) stageA(t & 1, 0, (long)(t + 2) * 64);
      SCHED0; BARR; LGKM0; SCHED0;
      mfmaQ(bfl, 4, 0);
      // q3
      if (s2) stageB(t & 1, 1, (long)(t + 2) * 64);
      if (s1) { if (s2) { VM(6); } else { VM(2); } }
      SCHED0; BARR; SCHED0;
      mfmaQ(bfh, 4, 2);
    }
  } else {
    s16x8 af[4], bf[4];
    auto loadKS = [&](const short* as, const short* bs, int ks){
      #pragma unroll
      for (int mi = 0; mi < 4; ++mi){
        int R = mi * 64 + wr * 16 + lr;
        af[mi] = *(const s16x8*)&as[R * 64 + (((ks * 4 + lg) ^ (R & 7)) << 3)];
      }
      #pragma unroll
      for (int ni = 0; ni < 4; ++ni){
        int R = wc * 64 + ni * 16 + lr;
        bf[ni] = *(const s16x8*)&bs[R * 64 + (((ks * 4 + lg) ^ (R & 7)) << 3)];
      }
    };
    auto mfmaP = [&](int nib){
      __builtin_amdgcn_s_setprio(1);
      #pragma unroll
      for (int mi = 0; mi < 4; ++mi)
        #pragma unroll
        for (int ni = 0; ni < 2; ++ni)
          acc[mi][nib + ni] = __builtin_amdgcn_mfma_f32_16x16x32_bf16(
              af[mi], bf[nib + ni], acc[mi][nib + ni], 0, 0, 0);
      __builtin_amdgcn_s_setprio(0);
    };

    // prologue: A0(0),A1(0) -> buf0; B(0); A0(1),A1(1) -> buf1
    stageA(0,0,0); stageA(0,1,0); stageB(0,0,0);
    stageA(1,0,64); stageA(1,1,64);
    VM(4); SCHED0; BARR; SCHED0;
    int ta = 0, ta2 = 2;
    for (int t = 0; t < NT; ++t){
      const short* as = &AsM[ta * (256 * 64)];
      const short* bs = &BsM[(t & 1) * (128 * 64)];
      const bool s1 = (t + 1 < NT), s2 = (t + 2 < NT);
      // q0: reads ks0; stage B(t+1)
      loadKS(as, bs, 0);
      if (s1) stageB((t + 1) & 1, 0, (long)(t + 1) * 64);
      SCHED0; BARR; LGKM0; SCHED0;
      mfmaP(0);
      // q1: stage A0(t+2)
      if (s2) stageA(ta2, 0, (long)(t + 2) * 64);
      SCHED0; BARR; SCHED0;
      mfmaP(2);
      // q2: reads ks1; stage A1(t+2)
      loadKS(as, bs, 1);
      if (s2) stageA(ta2, 1, (long)(t + 2) * 64);
      SCHED0; BARR; LGKM0; SCHED0;
      mfmaP(0);
      // q3
      if (s2) { VM(4); } else { VM(0); }
      SCHED0; BARR; SCHED0;
      mfmaP(2);
      ta = (ta == 2) ? 0 : ta + 1;
      ta2 = (ta2 == 2) ? 0 : ta2 + 1;
    }
  }

  SCHED0;
  // epilogue: C/D layout col = lane&15, row = (lane>>4)*4 + reg
  const int rb = lg * 4;
  #pragma unroll
  for (int mi = 0; mi < MI; ++mi){
    #pragma unroll
    for (int ni = 0; ni < NI; ++ni){
      int cl = (int)bcol0 + ((CFG == 0) ? (ni * 64 + wc * 16 + lr)
                                        : (wc * 64 + ni * 16 + lr));
      float bv = bias[cl];
      #pragma unroll
      for (int i = 0; i < 4; ++i){
        long rl = arow0 + ((CFG == 0) ? (mi * 32 + wr * 16) : (mi * 64 + wr * 16)) + rb + i;
        float v = acc[mi][ni][i] + bv;
        if constexpr (EPI == 0){
          Hout[rl * (long)N + cl] = f2bf(gelu_f(v));
        } else {
          float rr = bf2f(resid[(row0_abs + rl) * 1024 + cl]);
          Fout[(row0_abs + rl) * 1024 + cl] = v + rr;
        }
      }
    }
  }
}

// ---------------- LN2 in-place on f32 out ----------------
__global__ __launch_bounds__(256) void ln2_k(float* __restrict__ out,
    const float* __restrict__ g, const float* __restrict__ bb){
  size_t row = blockIdx.x;
  int tid = threadIdx.x;
  float* p = out + row * 1024;
  f32x4 v = *(const f32x4*)(p + tid * 4);
  float sum = v[0] + v[1] + v[2] + v[3];
  float sq  = v[0]*v[0] + v[1]*v[1] + v[2]*v[2] + v[3]*v[3];
  for (int off = 32; off; off >>= 1){ sum += __shfl_down(sum, off); sq += __shfl_down(sq, off); }
  __shared__ float rs[4], rq[4];
  int lane = tid & 63, w = tid >> 6;
  if (lane == 0){ rs[w] = sum; rq[w] = sq; }
  __syncthreads();
  sum = rs[0] + rs[1] + rs[2] + rs[3]; sq = rq[0] + rq[1] + rq[2] + rq[3];
  float mu = sum * (1.0f / 1024.0f);
  float var = sq * (1.0f / 1024.0f) - mu * mu;
  float sc = rsqrtf(var + 1e-5f);
  f32x4 o;
  #pragma unroll
  for (int j = 0; j < 4; ++j){
    int d = tid * 4 + j;
    o[j] = (v[j] - mu) * sc * g[d] + bb[d];
  }
  *(f32x4*)(p + tid * 4) = o;
}

// ---------------- launch ----------------
extern "C" void kernel_launch(void* const* d_in, const int* in_sizes, int n_in,
                              void* d_out, int out_size, void* d_ws, size_t ws_size,
                              hipStream_t stream){
  (void)in_sizes; (void)n_in; (void)out_size; (void)ws_size;
  const int*   tokens = (const int*)d_in[0];
  const float* frw  = (const float*)d_in[1];
  const float* fiw  = (const float*)d_in[2];
  const float* mw   = (const float*)d_in[3];
  const float* po   = (const float*)d_in[4];
  const float* ftew = (const float*)d_in[5];
  const float* fteb = (const float*)d_in[6];
  const float* posph= (const float*)d_in[7];
  const float* awr  = (const float*)d_in[8];
  const float* awi  = (const float*)d_in[9];
  const float* ln1g = (const float*)d_in[10];
  const float* ln1b = (const float*)d_in[11];
  const float* w1   = (const float*)d_in[12];
  const float* b1   = (const float*)d_in[13];
  const float* w2   = (const float*)d_in[14];
  const float* b2   = (const float*)d_in[15];
  const float* ln2g = (const float*)d_in[16];
  const float* ln2b = (const float*)d_in[17];
  float* out = (float*)d_out;

  char* ws = (char*)d_ws;
  size_t o = 0;
  float* residual = (float*)(ws + o); o += (size_t)16384 * 1024 * 4;  // 67.1 MB; later hbuf
  short* xln1     = (short*)(ws + o); o += (size_t)16384 * 1024 * 2;  // 33.6 MB
  short* w1b      = (short*)(ws + o); o += (size_t)4096 * 1024 * 2;
  short* w2b      = (short*)(ws + o); o += (size_t)4096 * 1024 * 2;
  float* ctab     = (float*)(ws + o); o += 524288;
  float* stab     = (float*)(ws + o); o += 524288;
  float* Xr       = (float*)(ws + o); o += 524288;
  float* Xi       = (float*)(ws + o); o += 524288;
  float* Or       = (float*)(ws + o); o += 524288;
  float* Oi       = (float*)(ws + o); o += 524288;
  float* Pr       = (float*)(ws + o); o += (size_t)8 * 4 * 1024 * 32 * 4;
  float* Pi       = (float*)(ws + o); o += (size_t)8 * 4 * 1024 * 32 * 4;
  float* wcs      = (float*)(ws + o); o += 512;
  short* hbuf     = (short*)residual;   // 8192x4096 bf16 aliases dead residual

  prep_wcs_k<<<1, 64, 0, stream>>>(mw, po, wcs);
  prep_tab_k<<<512, 256, 0, stream>>>(ctab, stab);
  transpose_bf16_k<<<dim3(64, 16), 256, 0, stream>>>(w1, w1b, 1024, 4096);
  transpose_bf16_k<<<dim3(16, 64), 256, 0, stream>>>(w2, w2b, 4096, 1024);

  kernelA<<<4096, 256, 0, stream>>>(tokens, frw, fiw, wcs, ftew, fteb, posph, residual);
  kernelB2<<<1024, 256, 0, stream>>>(residual, Pr, Pi);
  reduceB_k<<<512, 256, 0, stream>>>(Pr, Pi, Xr, Xi);
  kernelC<<<256, 128, 0, stream>>>(Xr, Xi, awr, awi, Or, Oi);
  kernelD3<<<2048, 256, 0, stream>>>(Or, Oi, ctab, stab, residual);
  ln1_k<<<16384, 256, 0, stream>>>(residual, ln1g, ln1b, xln1);

  for (int c = 0; c < 2; ++c){
    long row0 = (long)c * 8192;
    gemm8p_k<0, 0><<<512, 512, 0, stream>>>(xln1 + row0 * 1024, w1b, b1,
                                            nullptr, hbuf, nullptr, 1024, 4096, 0);
    gemm8p_k<1, 1><<<256, 512, 0, stream>>>(hbuf, w2b, b2,
                                            xln1, nullptr, out, 4096, 1024, row0);
  }
  ln2_k<<<16384, 256, 0, stream>>>(out, ln2g, ln2b);
}

// Round 7
// 549.407 us; speedup vs baseline: 1.8549x; 1.0221x over previous
//
#include <hip/hip_runtime.h>

// WaveInputEncoder on MI355X — round 7.
// vs r6: GEMMs keep the verified 4-phase/1-barrier schedule + vmcnt ledger, but
// addressing is rebuilt: ds_read = 4 precomputed swizzled bases + compile-time
// offset immediates (BUF literal via unroll-by-2 macros); staging = uniform
// SGPR part + one per-lane offset (saddr form). CFG1 = same skeleton, NI=2,
// A/B double-buffered (96 KB), rederived vmcnt counts. Rest unchanged.

typedef __attribute__((ext_vector_type(8))) short s16x8;
typedef __attribute__((ext_vector_type(4))) short s16x4;
typedef __attribute__((ext_vector_type(4))) float f32x4;

#define SCHED0 __builtin_amdgcn_sched_barrier(0)
#define BARR   __builtin_amdgcn_s_barrier()
#define LGKM0  asm volatile("s_waitcnt lgkmcnt(0)" ::: "memory")
#define VM(n)  asm volatile("s_waitcnt vmcnt(" #n ")" ::: "memory")

__device__ __forceinline__ short f2bf(float x){
  unsigned u = __float_as_uint(x);
  unsigned r = (u + 0x7fffu + ((u >> 16) & 1u)) >> 16;   // RNE
  return (short)r;
}
__device__ __forceinline__ float bf2f(short x){
  return __uint_as_float(((unsigned)(unsigned short)x) << 16);
}
__device__ __forceinline__ void gload16(const void* g, void* l){
  __builtin_amdgcn_global_load_lds((const __attribute__((address_space(1))) void*)g,
                                   (__attribute__((address_space(3))) void*)l, 16, 0, 0);
}
__device__ __forceinline__ float gelu_f(float v){
  float u2 = v * (0.7978845608f + 0.0356774081f * v * v);
  float e = __expf(2.0f * u2);
  float th = 1.0f - 2.0f / (e + 1.0f);
  return 0.5f * v * (1.0f + th);
}

// ---------------- prep kernels ----------------
__global__ void prep_wcs_k(const float* __restrict__ mw, const float* __restrict__ po,
                           float* __restrict__ wcs){
  int i = threadIdx.x;
  if (i < 32){
    wcs[i]      = log1pf(expf(mw[i]));  // softplus
    wcs[32 + i] = cosf(po[i]);
    wcs[64 + i] = sinf(po[i]);
  }
}

__global__ __launch_bounds__(256) void prep_tab_k(float* __restrict__ ctab, float* __restrict__ stab){
  int idx = blockIdx.x * 256 + threadIdx.x;      // idx = m*4096 + t
  int m = idx >> 12, t = idx & 4095;
  int r = (m * t) & 4095;
  float ang = (float)r * 1.5339807878856412e-3f; // 2*pi/4096
  float s, c; sincosf(ang, &s, &c);
  ctab[idx] = c; stab[idx] = s;
}

// transpose fp32 (R x C) -> bf16 (C x R), 64x64 LDS tiles
__global__ __launch_bounds__(256) void transpose_bf16_k(const float* __restrict__ src,
                                                        short* __restrict__ dst,
                                                        int R, int C){
  __shared__ float tile[64][65];
  int c0 = blockIdx.x * 64, r0 = blockIdx.y * 64;
  for (int i = 0; i < 16; ++i){
    int idx = i * 256 + threadIdx.x;
    int rr = idx >> 6, cc = idx & 63;
    tile[rr][cc] = src[(size_t)(r0 + rr) * C + c0 + cc];
  }
  __syncthreads();
  for (int i = 0; i < 16; ++i){
    int idx = i * 256 + threadIdx.x;
    int cc = idx >> 6, rr = idx & 63;
    dst[(size_t)(c0 + cc) * R + r0 + rr] = f2bf(tile[rr][cc]);
  }
}

// ---------------- kernel A ----------------
__global__ __launch_bounds__(256) void kernelA(const int* __restrict__ tokens,
    const float* __restrict__ frw, const float* __restrict__ fiw,
    const float* __restrict__ wcs, const float* __restrict__ ftew,
    const float* __restrict__ fteb, const float* __restrict__ posph,
    float* __restrict__ xout){
  __shared__ float ffs[4][64];
  __shared__ float xs[4][1024];
  __shared__ float wsh[96];
  int tid = threadIdx.x;
  int b = blockIdx.x >> 10, t0 = (blockIdx.x & 1023) * 4;
  if (tid < 96) wsh[tid] = wcs[tid];
  __syncthreads();
  if (tid < 128){
    int tk = tid >> 5, m = tid & 31;
    int tok = tokens[b * 4096 + t0 + tk];
    float w = wsh[m];
    float re = frw[(size_t)tok * 32 + m] * w;
    float im = fiw[(size_t)tok * 32 + m] * w;
    float c = wsh[32 + m], s = wsh[64 + m];
    ffs[tk][m]      = re * c - im * s;
    ffs[tk][32 + m] = re * s + im * c;
  }
  __syncthreads();
  for (int p = 0; p < 4; ++p){
    int dd = p * 256 + tid;
    float bb = fteb[dd];
    float a0 = bb, a1 = bb, a2 = bb, a3 = bb;
    #pragma unroll 8
    for (int k = 0; k < 64; ++k){
      float wv = ftew[k * 1024 + dd];
      a0 += ffs[0][k] * wv; a1 += ffs[1][k] * wv;
      a2 += ffs[2][k] * wv; a3 += ffs[3][k] * wv;
    }
    xs[0][dd] = a0; xs[1][dd] = a1; xs[2][dd] = a2; xs[3][dd] = a3;
  }
  __syncthreads();
  for (int p = 0; p < 4; ++p){
    int dd = p * 256 + tid, dm = (dd + 1023) & 1023;
    #pragma unroll
    for (int tk = 0; tk < 4; ++tk){
      float pp = posph[(size_t)(t0 + tk) * 1024 + dd];
      float p2 = pp * pp;
      float sp = pp * (1.0f - p2 * (1.0f/6.0f) + p2 * p2 * (1.0f/120.0f));
      float cp = 1.0f - p2 * 0.5f + p2 * p2 * (1.0f/24.0f);
      xout[((size_t)b * 4096 + t0 + tk) * 1024 + dd] = xs[tk][dd] * cp + xs[tk][dm] * sp;
    }
  }
}

// ---------------- kernel B: truncated forward DFT via rotation recurrence ----------------
__global__ __launch_bounds__(256) void kernelB2(const float* __restrict__ xin,
    float* __restrict__ Pr, float* __restrict__ Pi){
  __shared__ float xsh[64][32];
  int tid = threadIdx.x;
  int bx = blockIdx.x;
  int b = bx >> 8, dch = (bx >> 3) & 31, tc = bx & 7;
  int d0 = dch * 32;
  int t_start = tc * 512;
  int dg = tid >> 5, m = tid & 31;
  const float TPN = 1.5339807878856412e-3f;
  int r0 = (m * t_start) & 4095;
  float cw, sw; sincosf(-(float)r0 * TPN, &sw, &cw);
  float cs, ss; sincosf(-(float)m * TPN, &ss, &cs);
  float ar[4] = {0,0,0,0}, ai[4] = {0,0,0,0};
  for (int t0 = t_start; t0 < t_start + 512; t0 += 64){
    __syncthreads();
    #pragma unroll
    for (int i = 0; i < 2; ++i){
      int unit = i * 256 + tid;
      int tt = unit >> 3, du = (unit & 7) * 4;
      *(f32x4*)&xsh[tt][du] = *(const f32x4*)&xin[((size_t)b * 4096 + t0 + tt) * 1024 + d0 + du];
    }
    __syncthreads();
    #pragma unroll 4
    for (int tt = 0; tt < 64; ++tt){
      f32x4 xv = *(const f32x4*)&xsh[tt][dg * 4];
      #pragma unroll
      for (int j = 0; j < 4; ++j){ ar[j] += xv[j] * cw; ai[j] += xv[j] * sw; }
      float cn = cw * cs - sw * ss;
      sw = cw * ss + sw * cs; cw = cn;
    }
  }
  #pragma unroll
  for (int j = 0; j < 4; ++j){
    int d = d0 + dg * 4 + j;
    size_t idx = (((size_t)tc * 4 + b) * 1024 + d) * 32 + m;
    Pr[idx] = ar[j]; Pi[idx] = ai[j];
  }
}

__global__ __launch_bounds__(256) void reduceB_k(const float* __restrict__ Pr,
    const float* __restrict__ Pi, float* __restrict__ Xr, float* __restrict__ Xi){
  int lin = blockIdx.x * 256 + threadIdx.x;
  int m = lin & 31, d = (lin >> 5) & 1023, b = lin >> 15;
  float sr = 0.0f, si = 0.0f;
  for (int tc = 0; tc < 8; ++tc){
    size_t idx = (((size_t)tc * 4 + b) * 1024 + d) * 32 + m;
    sr += Pr[idx]; si += Pi[idx];
  }
  int n = d >> 7, jj = d & 127;
  size_t o = (((size_t)b * 8 + n) * 32 + m) * 128 + jj;
  Xr[o] = sr * 0.015625f; Xi[o] = si * 0.015625f;
}

// ---------------- kernel C ----------------
__global__ __launch_bounds__(128) void kernelC(const float* __restrict__ Xr, const float* __restrict__ Xi,
    const float* __restrict__ awr, const float* __restrict__ awi,
    float* __restrict__ Or, float* __restrict__ Oi){
  __shared__ float xr_s[4][128], xi_s[4][128];
  int nm = blockIdx.x; int n = nm >> 5, m = nm & 31;
  int i = threadIdx.x;
  for (int b = 0; b < 4; ++b){
    size_t src = (((size_t)b * 8 + n) * 32 + m) * 128 + i;
    xr_s[b][i] = Xr[src]; xi_s[b][i] = Xi[src];
  }
  __syncthreads();
  float accr[4] = {0,0,0,0}, acci[4] = {0,0,0,0};
  size_t wb = (((size_t)n * 32 + m) * 128 + i) * 128;
  for (int j = 0; j < 128; ++j){
    float wr = awr[wb + j], wi = awi[wb + j];
    #pragma unroll
    for (int b = 0; b < 4; ++b){
      accr[b] += wr * xr_s[b][j] - wi * xi_s[b][j];
      acci[b] += wr * xi_s[b][j] + wi * xr_s[b][j];
    }
  }
  #pragma unroll
  for (int b = 0; b < 4; ++b){
    float vr = accr[b], vi = acci[b];
    vr = vr > 0.01f ? vr - 0.01f : (vr < -0.01f ? vr + 0.01f : 0.0f);
    vi = vi > 0.01f ? vi - 0.01f : (vi < -0.01f ? vi + 0.01f : 0.0f);
    size_t dst = ((size_t)b * 32 + m) * 1024 + n * 128 + i;  // [b][m][d]
    Or[dst] = vr; Oi[dst] = vi;
  }
}

// ---------------- kernel D3: d-chunked irfft + residual in-place ----------------
__global__ __launch_bounds__(256) void kernelD3(const float* __restrict__ Or, const float* __restrict__ Oi,
    const float* __restrict__ ctab, const float* __restrict__ stab, float* __restrict__ y){
  __shared__ float cts[32][64], sts[32][64];
  __shared__ float Ors[32][144], Ois[32][144];
  int tid = threadIdx.x;
  int bx = blockIdx.x;
  int b = bx >> 9, tc = (bx >> 3) & 63, dc = bx & 7;
  int t0 = tc * 64, d0 = dc * 128;
  for (int i = 0; i < 8; ++i){
    int lin = i * 256 + tid;
    int m = lin >> 6, tl = lin & 63;
    float f = (m == 0 ? 1.0f : 2.0f) * 0.015625f;
    cts[m][tl] = ctab[m * 4096 + t0 + tl] * f;
    sts[m][tl] = stab[m * 4096 + t0 + tl] * f;
  }
  for (int i = 0; i < 4; ++i){
    int lin = i * 256 + tid;
    int m = lin >> 5, q = lin & 31;
    int w = q * 4;
    int ph = w + ((w >> 5) << 2);
    size_t src = ((size_t)b * 32 + m) * 1024 + d0 + w;
    *(f32x4*)&Ors[m][ph] = *(const f32x4*)&Or[src];
    *(f32x4*)&Ois[m][ph] = *(const f32x4*)&Oi[src];
  }
  __syncthreads();
  int tt = tid >> 4, dl = tid & 15;
  int wb0 = dl * 8;
  int ph0 = wb0 + ((wb0 >> 5) << 2);
  int ph1 = ph0 + 4;
  float acc[4][8];
  #pragma unroll
  for (int q = 0; q < 4; ++q)
    #pragma unroll
    for (int j = 0; j < 8; ++j) acc[q][j] = 0.f;
  for (int m = 0; m < 32; ++m){
    f32x4 cv = *(const f32x4*)&cts[m][tt * 4];
    f32x4 sv = *(const f32x4*)&sts[m][tt * 4];
    f32x4 orv0 = *(const f32x4*)&Ors[m][ph0];
    f32x4 orv1 = *(const f32x4*)&Ors[m][ph1];
    f32x4 oiv0 = *(const f32x4*)&Ois[m][ph0];
    f32x4 oiv1 = *(const f32x4*)&Ois[m][ph1];
    #pragma unroll
    for (int q = 0; q < 4; ++q){
      #pragma unroll
      for (int e = 0; e < 4; ++e){
        acc[q][e]     += cv[q] * orv0[e] - sv[q] * oiv0[e];
        acc[q][4 + e] += cv[q] * orv1[e] - sv[q] * oiv1[e];
      }
    }
  }
  #pragma unroll
  for (int q = 0; q < 4; ++q){
    size_t row = ((size_t)b * 4096 + t0 + tt * 4 + q) * 1024 + d0 + dl * 8;
    f32x4 r0 = *(const f32x4*)&y[row];
    f32x4 r1 = *(const f32x4*)&y[row + 4];
    #pragma unroll
    for (int e = 0; e < 4; ++e){ r0[e] += acc[q][e]; r1[e] += acc[q][4 + e]; }
    *(f32x4*)&y[row] = r0;
    *(f32x4*)&y[row + 4] = r1;
  }
}

// ---------------- LN1: y (f32) -> xln1 (bf16) ----------------
__global__ __launch_bounds__(256) void ln1_k(const float* __restrict__ y,
    const float* __restrict__ g, const float* __restrict__ bb, short* __restrict__ xln){
  size_t row = blockIdx.x;
  int tid = threadIdx.x;
  f32x4 v = *(const f32x4*)(y + row * 1024 + tid * 4);
  float sum = v[0] + v[1] + v[2] + v[3];
  float sq  = v[0]*v[0] + v[1]*v[1] + v[2]*v[2] + v[3]*v[3];
  for (int off = 32; off; off >>= 1){ sum += __shfl_down(sum, off); sq += __shfl_down(sq, off); }
  __shared__ float rs[4], rq[4];
  int lane = tid & 63, w = tid >> 6;
  if (lane == 0){ rs[w] = sum; rq[w] = sq; }
  __syncthreads();
  sum = rs[0] + rs[1] + rs[2] + rs[3]; sq = rq[0] + rq[1] + rq[2] + rq[3];
  float mu = sum * (1.0f / 1024.0f);
  float var = sq * (1.0f / 1024.0f) - mu * mu;
  float sc = rsqrtf(var + 1e-5f);
  s16x4 o;
  #pragma unroll
  for (int j = 0; j < 4; ++j){
    int d = tid * 4 + j;
    o[j] = f2bf((v[j] - mu) * sc * g[d] + bb[d]);
  }
  *(s16x4*)(xln + row * 1024 + tid * 4) = o;
}

// ================= GEMM shared macros =================
// ds_read: precomputed per-thread bases + compile-time offset immediates.
#define LA4(BUF, MIB) { _Pragma("unroll") for (int mi = 0; mi < 4; ++mi){ \
    af[mi][0] = *(const s16x8*)&AsM[(BUF)*16384 + ((MIB)+mi)*2048 + aBase0]; \
    af[mi][1] = *(const s16x8*)&AsM[(BUF)*16384 + ((MIB)+mi)*2048 + aBase1]; } }

// ---------------- GEMM1: 256x256, 8 waves 2Mx4N, K=1024, gelu->bf16 ----------------
__global__ __launch_bounds__(512, 2) void gemm1_k(const short* __restrict__ A,
    const short* __restrict__ BT, const float* __restrict__ bias,
    short* __restrict__ Hout){
  constexpr int K = 1024, NT = 16, N = 4096;
  __shared__ __align__(16) short AsM[2 * 16384];
  __shared__ __align__(16) short BsM[2 * 16384];
  const int tid = threadIdx.x;
  const int lane = tid & 63, wv = tid >> 6;
  const int wr = wv >> 2, wc = wv & 3;
  const int lr = lane & 15, lg = lane >> 4;
  int flat = blockIdx.x;
  int xcd = flat & 7, l = flat >> 3;
  int mb = (xcd & 3) * 8 + (l & 7);
  int nb = (xcd >> 2) * 8 + (l >> 3);
  const int arow0 = mb * 256, bcol0 = nb * 256;

  const int rA = wr * 16 + lr, rB = wc * 16 + lr;
  const int aBase0 = rA * 64 + ((lg       ^ (rA & 7)) * 8);
  const int aBase1 = rA * 64 + (((4 + lg) ^ (rA & 7)) * 8);
  const int bBase0 = rB * 64 + ((lg       ^ (rB & 7)) * 8);
  const int bBase1 = rB * 64 + (((4 + lg) ^ (rB & 7)) * 8);

  const int rr = tid >> 3;
  const int sl8 = ((tid & 7) ^ (rr & 7)) * 8;
  const long aoff = (long)rr * K + sl8;           // per-lane, in shorts
  const short* Au = A  + (long)arow0 * K;         // uniform
  const short* Bu = BT + (long)bcol0 * K;
  const int ldsw = wv * 512;                      // per-wave staging slot (shorts)

#define SA1(BUF,H,T) { \
  gload16(Au + (long)((H)*128      )*K + (T)*64 + aoff, AsM + (BUF)*16384 + (H)*8192 + ldsw); \
  gload16(Au + (long)((H)*128 + 64 )*K + (T)*64 + aoff, AsM + (BUF)*16384 + (H)*8192 + 4096 + ldsw); }
#define SB1(BUF,H,T) { \
  gload16(Bu + (long)((H)*128      )*K + (T)*64 + aoff, BsM + (BUF)*16384 + (H)*8192 + ldsw); \
  gload16(Bu + (long)((H)*128 + 64 )*K + (T)*64 + aoff, BsM + (BUF)*16384 + (H)*8192 + 4096 + ldsw); }
#define LB2(BUF, DST, NIB) { _Pragma("unroll") for (int ni = 0; ni < 2; ++ni){ \
    DST[ni][0] = *(const s16x8*)&BsM[(BUF)*16384 + ((NIB)+ni)*4096 + bBase0]; \
    DST[ni][1] = *(const s16x8*)&BsM[(BUF)*16384 + ((NIB)+ni)*4096 + bBase1]; } }
#define MQ1(BF, MIB, NIB) { __builtin_amdgcn_s_setprio(1); \
  _Pragma("unroll") for (int ks = 0; ks < 2; ++ks) \
  _Pragma("unroll") for (int mi = 0; mi < 4; ++mi) \
  _Pragma("unroll") for (int ni = 0; ni < 2; ++ni) \
    acc[(MIB)+mi][(NIB)+ni] = __builtin_amdgcn_mfma_f32_16x16x32_bf16( \
        af[mi][ks], BF[ni][ks], acc[(MIB)+mi][(NIB)+ni], 0, 0, 0); \
  __builtin_amdgcn_s_setprio(0); }

  f32x4 acc[8][4] = {};
  s16x8 af[4][2], bfl[2][2], bfh[2][2];

  // prologue: tile0 full + tile1 partial (A h0, B h1)
  SA1(0,0,0); SB1(0,1,0); SB1(0,0,0); SA1(0,1,0); SA1(1,0,1); SB1(1,1,1);
  VM(6); SCHED0; BARR; SCHED0;

#define T1(T, BUF) { const bool s1 = (T)+1 < NT, s2 = (T)+2 < NT; \
  LA4(BUF,0); LB2(BUF,bfl,0); \
  if (s1) SB1(1-(BUF),0,(T)+1); \
  SCHED0; BARR; LGKM0; SCHED0; \
  MQ1(bfl,0,0); \
  LB2(BUF,bfh,2); \
  if (s1) SA1(1-(BUF),1,(T)+1); \
  if (s1) { VM(8); } else { VM(0); } \
  SCHED0; BARR; LGKM0; SCHED0; \
  MQ1(bfh,0,2); \
  LA4(BUF,4); \
  if (s2) SA1(BUF,0,(T)+2); \
  SCHED0; BARR; LGKM0; SCHED0; \
  MQ1(bfl,4,0); \
  if (s2) SB1(BUF,1,(T)+2); \
  if (s1) { if (s2) { VM(6); } else { VM(2); } } \
  SCHED0; BARR; SCHED0; \
  MQ1(bfh,4,2); }

  for (int t2 = 0; t2 < NT; t2 += 2){
    T1(t2, 0);
    T1(t2 + 1, 1);
  }
#undef T1
#undef SA1
#undef SB1
#undef LB2
#undef MQ1

  SCHED0;
  const int rb = lg * 4;
  #pragma unroll
  for (int mi = 0; mi < 8; ++mi){
    #pragma unroll
    for (int ni = 0; ni < 4; ++ni){
      int cl = bcol0 + ni * 64 + wc * 16 + lr;
      float bv = bias[cl];
      #pragma unroll
      for (int i = 0; i < 4; ++i){
        long rl = arow0 + mi * 32 + wr * 16 + rb + i;
        float v = acc[mi][ni][i] + bv;
        Hout[rl * (long)N + cl] = f2bf(gelu_f(v));
      }
    }
  }
}

// ---------------- GEMM2: 256x128, 8 waves 2Mx4N (NI=2), K=4096, +bias+resid->f32 ----------------
__global__ __launch_bounds__(512, 2) void gemm2_k(const short* __restrict__ A,
    const short* __restrict__ BT, const float* __restrict__ bias,
    const short* __restrict__ resid, float* __restrict__ Fout, long row0_abs){
  constexpr int K = 4096, NT = 64;
  __shared__ __align__(16) short AsM[2 * 16384];
  __shared__ __align__(16) short BsM[2 * 8192];
  const int tid = threadIdx.x;
  const int lane = tid & 63, wv = tid >> 6;
  const int wr = wv >> 2, wc = wv & 3;
  const int lr = lane & 15, lg = lane >> 4;
  int flat = blockIdx.x;
  int xcd = flat & 7, l = flat >> 3;
  int mb = (xcd & 3) * 8 + (l & 7);
  int nb = (xcd >> 2) * 4 + (l >> 3);
  const int arow0 = mb * 256, bcol0 = nb * 128;

  const int rA = wr * 16 + lr, rB = wc * 16 + lr;
  const int aBase0 = rA * 64 + ((lg       ^ (rA & 7)) * 8);
  const int aBase1 = rA * 64 + (((4 + lg) ^ (rA & 7)) * 8);
  const int bBase0 = rB * 64 + ((lg       ^ (rB & 7)) * 8);
  const int bBase1 = rB * 64 + (((4 + lg) ^ (rB & 7)) * 8);

  const int rr = tid >> 3;
  const int sl8 = ((tid & 7) ^ (rr & 7)) * 8;
  const long aoff = (long)rr * K + sl8;
  const short* Au = A  + (long)arow0 * K;
  const short* Bu = BT + (long)bcol0 * K;
  const int ldsw = wv * 512;

#define SA2(BUF,H,T) { \
  gload16(Au + (long)((H)*128      )*K + (T)*64 + aoff, AsM + (BUF)*16384 + (H)*8192 + ldsw); \
  gload16(Au + (long)((H)*128 + 64 )*K + (T)*64 + aoff, AsM + (BUF)*16384 + (H)*8192 + 4096 + ldsw); }
#define SB2(BUF,H,T) \
  gload16(Bu + (long)((H)*64)*K + (T)*64 + aoff, BsM + (BUF)*8192 + (H)*4096 + ldsw);
#define LB1(BUF, DST, NI) { \
    DST[0] = *(const s16x8*)&BsM[(BUF)*8192 + (NI)*4096 + bBase0]; \
    DST[1] = *(const s16x8*)&BsM[(BUF)*8192 + (NI)*4096 + bBase1]; }
#define MQ2(BF, MIB, NI) { __builtin_amdgcn_s_setprio(1); \
  _Pragma("unroll") for (int ks = 0; ks < 2; ++ks) \
  _Pragma("unroll") for (int mi = 0; mi < 4; ++mi) \
    acc[(MIB)+mi][NI] = __builtin_amdgcn_mfma_f32_16x16x32_bf16( \
        af[mi][ks], BF[ks], acc[(MIB)+mi][NI], 0, 0, 0); \
  __builtin_amdgcn_s_setprio(0); }

  f32x4 acc[8][2] = {};
  s16x8 af[4][2], bfl[2], bfh[2];

  // prologue: tile0 full + tile1 partial (A h0 [2], B h1 [1]) -> keep 5
  SA2(0,0,0); SB2(0,1,0); SB2(0,0,0); SA2(0,1,0); SA2(1,0,1); SB2(1,1,1);
  VM(5); SCHED0; BARR; SCHED0;

#define T2(T, BUF) { const bool s1 = (T)+1 < NT, s2 = (T)+2 < NT; \
  LA4(BUF,0); LB1(BUF,bfl,0); \
  if (s1) SB2(1-(BUF),0,(T)+1); \
  SCHED0; BARR; LGKM0; SCHED0; \
  MQ2(bfl,0,0); \
  LB1(BUF,bfh,1); \
  if (s1) SA2(1-(BUF),1,(T)+1); \
  if (s1) { VM(6); } else { VM(0); } \
  SCHED0; BARR; LGKM0; SCHED0; \
  MQ2(bfh,0,1); \
  LA4(BUF,4); \
  if (s2) SA2(BUF,0,(T)+2); \
  SCHED0; BARR; LGKM0; SCHED0; \
  MQ2(bfl,4,0); \
  if (s2) SB2(BUF,1,(T)+2); \
  if (s1) { if (s2) { VM(5); } else { VM(2); } } \
  SCHED0; BARR; SCHED0; \
  MQ2(bfh,4,1); }

  for (int t2 = 0; t2 < NT; t2 += 2){
    T2(t2, 0);
    T2(t2 + 1, 1);
  }
#undef T2
#undef SA2
#undef SB2
#undef LB1
#undef MQ2

  SCHED0;
  const int rb = lg * 4;
  #pragma unroll
  for (int mi = 0; mi < 8; ++mi){
    #pragma unroll
    for (int ni = 0; ni < 2; ++ni){
      int cl = bcol0 + ni * 64 + wc * 16 + lr;
      float bv = bias[cl];
      #pragma unroll
      for (int i = 0; i < 4; ++i){
        long rl = arow0 + mi * 32 + wr * 16 + rb + i;
        float v = acc[mi][ni][i] + bv;
        float rv = bf2f(resid[(row0_abs + rl) * 1024 + cl]);
        Fout[(row0_abs + rl) * 1024 + cl] = v + rv;
      }
    }
  }
}

// ---------------- LN2 in-place on f32 out ----------------
__global__ __launch_bounds__(256) void ln2_k(float* __restrict__ out,
    const float* __restrict__ g, const float* __restrict__ bb){
  size_t row = blockIdx.x;
  int tid = threadIdx.x;
  float* p = out + row * 1024;
  f32x4 v = *(const f32x4*)(p + tid * 4);
  float sum = v[0] + v[1] + v[2] + v[3];
  float sq  = v[0]*v[0] + v[1]*v[1] + v[2]*v[2] + v[3]*v[3];
  for (int off = 32; off; off >>= 1){ sum += __shfl_down(sum, off); sq += __shfl_down(sq, off); }
  __shared__ float rs[4], rq[4];
  int lane = tid & 63, w = tid >> 6;
  if (lane == 0){ rs[w] = sum; rq[w] = sq; }
  __syncthreads();
  sum = rs[0] + rs[1] + rs[2] + rs[3]; sq = rq[0] + rq[1] + rq[2] + rq[3];
  float mu = sum * (1.0f / 1024.0f);
  float var = sq * (1.0f / 1024.0f) - mu * mu;
  float sc = rsqrtf(var + 1e-5f);
  f32x4 o;
  #pragma unroll
  for (int j = 0; j < 4; ++j){
    int d = tid * 4 + j;
    o[j] = (v[j] - mu) * sc * g[d] + bb[d];
  }
  *(f32x4*)(p + tid * 4) = o;
}

// ---------------- launch ----------------
extern "C" void kernel_launch(void* const* d_in, const int* in_sizes, int n_in,
                              void* d_out, int out_size, void* d_ws, size_t ws_size,
                              hipStream_t stream){
  (void)in_sizes; (void)n_in; (void)out_size; (void)ws_size;
  const int*   tokens = (const int*)d_in[0];
  const float* frw  = (const float*)d_in[1];
  const float* fiw  = (const float*)d_in[2];
  const float* mw   = (const float*)d_in[3];
  const float* po   = (const float*)d_in[4];
  const float* ftew = (const float*)d_in[5];
  const float* fteb = (const float*)d_in[6];
  const float* posph= (const float*)d_in[7];
  const float* awr  = (const float*)d_in[8];
  const float* awi  = (const float*)d_in[9];
  const float* ln1g = (const float*)d_in[10];
  const float* ln1b = (const float*)d_in[11];
  const float* w1   = (const float*)d_in[12];
  const float* b1   = (const float*)d_in[13];
  const float* w2   = (const float*)d_in[14];
  const float* b2   = (const float*)d_in[15];
  const float* ln2g = (const float*)d_in[16];
  const float* ln2b = (const float*)d_in[17];
  float* out = (float*)d_out;

  char* ws = (char*)d_ws;
  size_t o = 0;
  float* residual = (float*)(ws + o); o += (size_t)16384 * 1024 * 4;  // 67.1 MB; later hbuf
  short* xln1     = (short*)(ws + o); o += (size_t)16384 * 1024 * 2;  // 33.6 MB
  short* w1b      = (short*)(ws + o); o += (size_t)4096 * 1024 * 2;
  short* w2b      = (short*)(ws + o); o += (size_t)4096 * 1024 * 2;
  float* ctab     = (float*)(ws + o); o += 524288;
  float* stab     = (float*)(ws + o); o += 524288;
  float* Xr       = (float*)(ws + o); o += 524288;
  float* Xi       = (float*)(ws + o); o += 524288;
  float* Or       = (float*)(ws + o); o += 524288;
  float* Oi       = (float*)(ws + o); o += 524288;
  float* Pr       = (float*)(ws + o); o += (size_t)8 * 4 * 1024 * 32 * 4;
  float* Pi       = (float*)(ws + o); o += (size_t)8 * 4 * 1024 * 32 * 4;
  float* wcs      = (float*)(ws + o); o += 512;
  short* hbuf     = (short*)residual;   // 8192x4096 bf16 aliases dead residual

  prep_wcs_k<<<1, 64, 0, stream>>>(mw, po, wcs);
  prep_tab_k<<<512, 256, 0, stream>>>(ctab, stab);
  transpose_bf16_k<<<dim3(64, 16), 256, 0, stream>>>(w1, w1b, 1024, 4096);
  transpose_bf16_k<<<dim3(16, 64), 256, 0, stream>>>(w2, w2b, 4096, 1024);

  kernelA<<<4096, 256, 0, stream>>>(tokens, frw, fiw, wcs, ftew, fteb, posph, residual);
  kernelB2<<<1024, 256, 0, stream>>>(residual, Pr, Pi);
  reduceB_k<<<512, 256, 0, stream>>>(Pr, Pi, Xr, Xi);
  kernelC<<<256, 128, 0, stream>>>(Xr, Xi, awr, awi, Or, Oi);
  kernelD3<<<2048, 256, 0, stream>>>(Or, Oi, ctab, stab, residual);
  ln1_k<<<16384, 256, 0, stream>>>(residual, ln1g, ln1b, xln1);

  for (int c = 0; c < 2; ++c){
    long row0 = (long)c * 8192;
    gemm1_k<<<512, 512, 0, stream>>>(xln1 + row0 * 1024, w1b, b1, hbuf);
    gemm2_k<<<256, 512, 0, stream>>>(hbuf, w2b, b2, xln1, out, row0);
  }
  ln2_k<<<16384, 256, 0, stream>>>(out, ln2g, ln2b);
}